// Round 11
// baseline (3951.605 us; speedup 1.0000x reference)
//
#include <hip/hip_runtime.h>
#include <math.h>

// Residual VQ matching a float32 numpy reference (R3/R6/R7/R10-verified):
//   scores = x2 + e2 - 2*(res @ emb.T) in f32, argmin = first-min.
// R11: split B-feed to break LDS/MFMA co-saturation:
//   Bh (used by 2 of 3 MFMA passes) staged in LDS via linear global_load_lds;
//   Bl (1 pass) loaded per-lane straight from L2 into registers.
//   Codebook stored tile-swizzled in d_ws: [level][tile16KB][(s*8+kk)*1KB][lane*16B].
//   Packed-score top-2 (k in low-10 mantissa bits, offset+16, max+med3, no idx
//   regs); margin 8e-3 covers pack perturbation (<=3.9e-3) + true err (2.5e-4);
//   flagged rows -> exact replicated-f32 fixup kernel.

#define D_DIM 128
#define K_CB  1024
#define L_LVL 4
#define LK    (L_LVL * K_CB)
#define LKD   (LK * D_DIM)
#define NT2   16               // 16 tiles x 64 codewords
#define TILE_ELEMS 8192        // 64 cw x 128 dims
#define MARGIN_PACKED 8e-3f

typedef __bf16 bf16x8 __attribute__((ext_vector_type(8)));
typedef float  f32x16 __attribute__((ext_vector_type(16)));

// force f32 rounding of a product (blocks fma contraction)
static __device__ __forceinline__ float mulr(float a, float b) {
    float p = a * b; asm volatile("" : "+v"(p)); return p;
}

// ---------------- prep: swizzled bf16 hi/lo + pairwise e2 + flag zero ----------------
// chunk j: lane=j&63, kk=(j>>6)&7, s=(j>>9)&1, t=(j>>10)&15, lv=j>>14
// src row = lv*1024 + t*64 + s*32 + (lane&31), elems kk*16 + (lane>>5)*8 + 0..7
__global__ void rvq_prep(const float* __restrict__ cb,
                         __bf16* __restrict__ hi, __bf16* __restrict__ lo,
                         float* __restrict__ e2p, unsigned* __restrict__ flagcnt) {
    int j = blockIdx.x * blockDim.x + threadIdx.x;   // [0, LKD/8)
    if (j == 0) *flagcnt = 0;
    const int lane = j & 63, kk = (j >> 6) & 7, s = (j >> 9) & 1,
              t = (j >> 10) & 15, lv = j >> 14;
    const int row  = lv * K_CB + t * 64 + s * 32 + (lane & 31);
    const int elem = kk * 16 + (lane >> 5) * 8;
    const float* src = cb + (size_t)row * D_DIM + elem;
    float4 a = *(const float4*)src;
    float4 b = *(const float4*)(src + 4);
    float f[8] = {a.x, a.y, a.z, a.w, b.x, b.y, b.z, b.w};
    bf16x8 hv, lvv;
    #pragma unroll
    for (int e = 0; e < 8; ++e) {
        __bf16 h = (__bf16)f[e];
        hv[e]  = h;
        lvv[e] = (__bf16)(f[e] - (float)h);
    }
    *(bf16x8*)(hi + (size_t)j * 8) = hv;
    *(bf16x8*)(lo + (size_t)j * 8) = lvv;

    if (j < LK) {   // numpy-pairwise ||e||^2 for codeword row j
        const float* ep = cb + (size_t)j * D_DIM;
        float r8[8];
        #pragma unroll
        for (int q = 0; q < 8; ++q) r8[q] = mulr(ep[q], ep[q]);
        #pragma unroll
        for (int bb = 1; bb < 16; ++bb)
            #pragma unroll
            for (int q = 0; q < 8; ++q) r8[q] += mulr(ep[bb * 8 + q], ep[bb * 8 + q]);
        e2p[j] = ((r8[0] + r8[1]) + (r8[2] + r8[3])) + ((r8[4] + r8[5]) + (r8[6] + r8[7]));
    }
}

// ---------------- stage one 64-cw tile's hi into LDS (linear, coalesced) ----------------
static __device__ __forceinline__ void stage_tile(
    const __bf16* srcTile, __bf16* dst, int wave, int lane) {
    #pragma unroll
    for (int c = 0; c < 4; ++c) {
        const int it = wave * 4 + c;   // 1KB chunk id, 0..15
        __builtin_amdgcn_global_load_lds(
            (const __attribute__((address_space(1))) void*)(srcTile + it * 512 + lane * 8),
            (__attribute__((address_space(3))) void*)(dst + it * 512), 16, 0, 0);
    }
}

#define MFMA(A, Bv, C) __builtin_amdgcn_mfma_f32_32x32x16_bf16(A, Bv, C, 0, 0, 0)

// ---------------- MFMA hot kernel ----------------
__global__ __launch_bounds__(256)
void rvq_mfma(const float* __restrict__ residual,
              const float* __restrict__ codebooks,
              const __bf16* __restrict__ cbh, const __bf16* __restrict__ cbl,
              const float* __restrict__ e2p,
              unsigned* __restrict__ flagcnt, unsigned* __restrict__ flaglist,
              unsigned flagcap, float* __restrict__ out, int B) {
    __shared__ __align__(16) __bf16 bufh[2][TILE_ELEMS];   // 2 x 16 KB
    __shared__ float e2s[K_CB];                            // 4 KB
    __shared__ int   bidxs[L_LVL][128];
    __shared__ unsigned char flg[128];

    const int tid  = threadIdx.x;
    const int wave = tid >> 6;
    const int lane = tid & 63;
    const int col  = lane & 31;
    const int h    = lane >> 5;
    const int rb   = wave * 32;
    const int grow = blockIdx.x * 128 + rb + col;

    if (tid < 128) flg[tid] = 0;

    // A fragments: residual row split to bf16 hi/lo, in registers.
    bf16x8 Ah[8], Al[8];
    {
        const float* rowp = residual + (size_t)grow * D_DIM;
        #pragma unroll
        for (int kk = 0; kk < 8; ++kk) {
            const int d0 = kk * 16 + h * 8;
            float4 a = *(const float4*)(rowp + d0);
            float4 b = *(const float4*)(rowp + d0 + 4);
            float f[8] = {a.x, a.y, a.z, a.w, b.x, b.y, b.z, b.w};
            #pragma unroll
            for (int e = 0; e < 8; ++e) {
                __bf16 hh = (__bf16)f[e];
                Ah[kk][e] = hh;
                Al[kk][e] = (__bf16)(f[e] - (float)hh);
            }
        }
    }

    for (int l = 0; l < L_LVL; ++l) {
        const __bf16* cbhL = cbh + (size_t)l * NT2 * TILE_ELEMS;
        const __bf16* cblL = cbl + (size_t)l * NT2 * TILE_ELEMS;

        // level's e2 -> LDS, then drain all vmem (gathers/e2-load) so the
        // counted-vmcnt pipeline sees only its own loads.
        ((float4*)e2s)[tid] = ((const float4*)(e2p + l * K_CB))[tid];
        asm volatile("s_waitcnt vmcnt(0)" ::: "memory");

        // packed top-2 state (all real packed scores are >= ~2.0f)
        float rbest[16], rbest2[16];
        #pragma unroll
        for (int s = 0; s < 16; ++s) { rbest[s] = 0.f; rbest2[s] = 0.f; }

        stage_tile(cbhL + 0 * TILE_ELEMS, &bufh[0][0], wave, lane);
        stage_tile(cbhL + 1 * TILE_ELEMS, &bufh[1][0], wave, lane);

        for (int t = 0; t < NT2; ++t) {
            const __bf16* bh = &bufh[t & 1][0];
            if (t == 0) asm volatile("s_waitcnt vmcnt(4)" ::: "memory");
            __builtin_amdgcn_s_barrier();      // tile t resident; e2s visible
            __builtin_amdgcn_sched_barrier(0);

            // issue Bl (both subtiles) from L2 into registers
            const __bf16* blT = cblL + (size_t)t * TILE_ELEMS;
            bf16x8 Bl0[8], Bl1[8];
            #pragma unroll
            for (int kk = 0; kk < 8; ++kk)
                Bl0[kk] = *(const bf16x8*)(blT + kk * 512 + lane * 8);
            #pragma unroll
            for (int kk = 0; kk < 8; ++kk)
                Bl1[kk] = *(const bf16x8*)(blT + 4096 + kk * 512 + lane * 8);

            // acc init folds e2 and +16 offset: packed score = acc_final
            const float e2i0 = fmaf(-0.5f, e2s[t * 64 + col], 16.f);
            const float e2i1 = fmaf(-0.5f, e2s[t * 64 + 32 + col], 16.f);
            f32x16 accA0, accB0, accA1, accB1;
            #pragma unroll
            for (int s = 0; s < 16; ++s) {
                accA0[s] = e2i0; accB0[s] = 0.f;
                accA1[s] = e2i1; accB1[s] = 0.f;
            }

            __builtin_amdgcn_s_setprio(1);
            #pragma unroll
            for (int kk = 0; kk < 8; ++kk) {       // subtile 0: Bh passes
                bf16x8 Bh0 = *(const bf16x8*)(bh + kk * 512 + lane * 8);
                accA0 = MFMA(Ah[kk], Bh0, accA0);
                accB0 = MFMA(Al[kk], Bh0, accB0);
            }
            #pragma unroll
            for (int kk = 0; kk < 8; ++kk) {       // subtile 1: Bh passes
                bf16x8 Bh1 = *(const bf16x8*)(bh + 4096 + kk * 512 + lane * 8);
                accA1 = MFMA(Ah[kk], Bh1, accA1);
                accB1 = MFMA(Al[kk], Bh1, accB1);
            }
            __builtin_amdgcn_s_setprio(0);
            __builtin_amdgcn_sched_barrier(0);
            __builtin_amdgcn_s_barrier();          // all waves done reading bufh[t&1]
            asm volatile("" ::: "memory");
            if (t + 2 < NT2)
                stage_tile(cbhL + (size_t)(t + 2) * TILE_ELEMS, &bufh[t & 1][0], wave, lane);
            // Bl landed (leave only stage(t+2) in flight)
            if (t + 2 < NT2) asm volatile("s_waitcnt vmcnt(4)" ::: "memory");
            else             asm volatile("s_waitcnt vmcnt(0)" ::: "memory");
            __builtin_amdgcn_sched_barrier(0);

            __builtin_amdgcn_s_setprio(1);
            #pragma unroll
            for (int kk = 0; kk < 8; ++kk) accB0 = MFMA(Ah[kk], Bl0[kk], accB0);
            #pragma unroll
            for (int kk = 0; kk < 8; ++kk) accB1 = MFMA(Ah[kk], Bl1[kk], accB1);
            __builtin_amdgcn_s_setprio(0);

            // packed-score top-2: k embedded in low 10 mantissa bits
            const unsigned pk0 = 1023u - (unsigned)(t * 64 + col);
            const unsigned pk1 = 1023u - (unsigned)(t * 64 + 32 + col);
            #pragma unroll
            for (int s = 0; s < 16; ++s) {
                float sc0 = accA0[s] + accB0[s];
                float p0 = __uint_as_float((__float_as_uint(sc0) & ~1023u) | pk0);
                rbest2[s] = __builtin_amdgcn_fmed3f(p0, rbest[s], rbest2[s]);
                rbest[s]  = fmaxf(rbest[s], p0);
                float sc1 = accA1[s] + accB1[s];
                float p1 = __uint_as_float((__float_as_uint(sc1) & ~1023u) | pk1);
                rbest2[s] = __builtin_amdgcn_fmed3f(p1, rbest[s], rbest2[s]);
                rbest[s]  = fmaxf(rbest[s], p1);
            }
        }

        // merge packed top-2 across the 32 cols (ties impossible: k embedded;
        // larger packed = better score, then lower k — matches first-min)
        #pragma unroll
        for (int s = 0; s < 16; ++s) {
            float b = rbest[s], b2 = rbest2[s];
            #pragma unroll
            for (int m = 1; m <= 16; m <<= 1) {
                float bo  = __shfl_xor(b,  m, 64);
                float b2o = __shfl_xor(b2, m, 64);
                float nb2 = fmaxf(fminf(b, bo), fmaxf(b2, b2o));
                b  = fmaxf(b, bo);
                b2 = nb2;
            }
            const int rloc = (s & 3) + 8 * (s >> 2) + 4 * h;   // verified C row map
            if (col == 0) {
                int ix = 1023 - (int)(__float_as_uint(b) & 1023u);
                bidxs[l][rb + rloc] = ix;
                if (b - b2 <= MARGIN_PACKED) flg[rb + rloc] = 1;
            }
        }
        __syncthreads();

        // residual update in f32 from exact codebook, re-split to bf16 pair
        {
            const int bi = bidxs[l][rb + col];
            const float* qp = codebooks + ((size_t)l * K_CB + bi) * D_DIM;
            #pragma unroll
            for (int kk = 0; kk < 8; ++kk) {
                const int d0 = kk * 16 + h * 8;
                float4 qa = *(const float4*)(qp + d0);
                float4 qb = *(const float4*)(qp + d0 + 4);
                float q[8] = {qa.x, qa.y, qa.z, qa.w, qb.x, qb.y, qb.z, qb.w};
                #pragma unroll
                for (int e = 0; e < 8; ++e) {
                    float r = ((float)Ah[kk][e] + (float)Al[kk][e]) - q[e];
                    __bf16 hh = (__bf16)r;
                    Ah[kk][e] = hh;
                    Al[kk][e] = (__bf16)(r - (float)hh);
                }
            }
        }
    }

    // quantized = r0 - r_final
    {
        const float* rowp = residual + (size_t)grow * D_DIM;
        float* op = out + (size_t)grow * D_DIM;
        #pragma unroll
        for (int kk = 0; kk < 8; ++kk) {
            const int d0 = kk * 16 + h * 8;
            float4 a = *(const float4*)(rowp + d0);
            float4 b = *(const float4*)(rowp + d0 + 4);
            float f[8] = {a.x, a.y, a.z, a.w, b.x, b.y, b.z, b.w};
            float o[8];
            #pragma unroll
            for (int e = 0; e < 8; ++e)
                o[e] = f[e] - ((float)Ah[kk][e] + (float)Al[kk][e]);
            *(float4*)(op + d0)     = make_float4(o[0], o[1], o[2], o[3]);
            *(float4*)(op + d0 + 4) = make_float4(o[4], o[5], o[6], o[7]);
        }
    }
    if (tid < 128) {
        int row = blockIdx.x * 128 + tid;
        float4* cp = (float4*)(out + (size_t)B * D_DIM + (size_t)row * L_LVL);
        *cp = make_float4((float)bidxs[0][tid], (float)bidxs[1][tid],
                          (float)bidxs[2][tid], (float)bidxs[3][tid]);
        if (flg[tid]) {
            unsigned pos = atomicAdd(flagcnt, 1u);
            if (pos < flagcap) flaglist[pos] = row;
        }
    }
}

// ---------------- fixup: replicated reference semantics per flagged row ----------------
__global__ __launch_bounds__(256, 1)
void rvq_fixup(const float* __restrict__ residual,
               const float* __restrict__ codebooks,
               const float* __restrict__ e2p,
               const unsigned* __restrict__ flagcnt,
               const unsigned* __restrict__ flaglist,
               unsigned flagcap, float* __restrict__ out, int B) {
    __shared__ float rbuf[D_DIM];
    __shared__ float r0buf[D_DIM];
    __shared__ float x2s;
    __shared__ float redS[256];
    __shared__ int   redK[256];
    __shared__ int   codes_s[L_LVL];

    unsigned n = *flagcnt;
    if (n > flagcap) n = flagcap;

    for (unsigned b = blockIdx.x; b < n; b += gridDim.x) {
        int row = (int)flaglist[b];
        if (threadIdx.x < 32) {
            float4 v = ((const float4*)(residual + (size_t)row * D_DIM))[threadIdx.x];
            *(float4*)&rbuf[threadIdx.x * 4]  = v;
            *(float4*)&r0buf[threadIdx.x * 4] = v;
        }
        __syncthreads();

        for (int l = 0; l < L_LVL; ++l) {
            const float* cbl = codebooks + (size_t)l * K_CB * D_DIM;
            if (threadIdx.x == 0) {
                float r8[8];
                #pragma unroll
                for (int q = 0; q < 8; ++q) r8[q] = mulr(rbuf[q], rbuf[q]);
                for (int bb = 1; bb < 16; ++bb)
                    #pragma unroll
                    for (int q = 0; q < 8; ++q) r8[q] += mulr(rbuf[bb * 8 + q], rbuf[bb * 8 + q]);
                x2s = ((r8[0] + r8[1]) + (r8[2] + r8[3])) + ((r8[4] + r8[5]) + (r8[6] + r8[7]));
            }
            __syncthreads();
            float x2 = x2s;

            float bS = 3.4e38f;
            int   bK = 0x7fffffff;
            for (int m = 0; m < 4; ++m) {
                int k = threadIdx.x + m * 256;
                const float4* ek = (const float4*)(cbl + (size_t)k * D_DIM);
                double dd = 0.0;
                for (int c = 0; c < 32; ++c) {
                    float4 v = ek[c];
                    dd = fma((double)v.x, (double)rbuf[c * 4 + 0], dd);
                    dd = fma((double)v.y, (double)rbuf[c * 4 + 1], dd);
                    dd = fma((double)v.z, (double)rbuf[c * 4 + 2], dd);
                    dd = fma((double)v.w, (double)rbuf[c * 4 + 3], dd);
                }
                float M = (float)dd;                 // fl32(exact dot)
                float A = x2 + e2p[l * K_CB + k];    // fl32(x2 + e2)
                float S = A - 2.0f * M;              // final f32 rounding
                if (S < bS || (S == bS && k < bK)) { bS = S; bK = k; }
            }
            redS[threadIdx.x] = bS; redK[threadIdx.x] = bK;
            __syncthreads();
            for (int s = 128; s > 0; s >>= 1) {
                if (threadIdx.x < (unsigned)s) {
                    float So = redS[threadIdx.x + s];
                    int   Ko = redK[threadIdx.x + s];
                    if (So < redS[threadIdx.x] ||
                        (So == redS[threadIdx.x] && Ko < redK[threadIdx.x])) {
                        redS[threadIdx.x] = So; redK[threadIdx.x] = Ko;
                    }
                }
                __syncthreads();
            }
            int bi = redK[0];
            if (threadIdx.x == 0) codes_s[l] = bi;
            if (threadIdx.x < 32) {
                float4 q = ((const float4*)(cbl + (size_t)bi * D_DIM))[threadIdx.x];
                float4* p = (float4*)&rbuf[threadIdx.x * 4];
                float4 x = *p;
                x.x -= q.x; x.y -= q.y; x.z -= q.z; x.w -= q.w;
                *p = x;
            }
            __syncthreads();
        }

        if (threadIdx.x < 32) {
            float4 a = *(float4*)&r0buf[threadIdx.x * 4];
            float4 r = *(float4*)&rbuf[threadIdx.x * 4];
            ((float4*)(out + (size_t)row * D_DIM))[threadIdx.x] =
                make_float4(a.x - r.x, a.y - r.y, a.z - r.z, a.w - r.w);
        }
        if (threadIdx.x == 0) {
            float4* cp = (float4*)(out + (size_t)B * D_DIM + (size_t)row * L_LVL);
            *cp = make_float4((float)codes_s[0], (float)codes_s[1],
                              (float)codes_s[2], (float)codes_s[3]);
        }
        __syncthreads();
    }
}

extern "C" void kernel_launch(void* const* d_in, const int* in_sizes, int n_in,
                              void* d_out, int out_size, void* d_ws, size_t ws_size,
                              hipStream_t stream) {
    const float* residual  = (const float*)d_in[0];
    const float* codebooks = (const float*)d_in[1];
    float* out = (float*)d_out;
    int B = in_sizes[0] / D_DIM;  // 131072

    const size_t E2_BYTES = LK * sizeof(float);          // 16 KB
    const size_t CB_BYTES = (size_t)LKD * 2;             // 1 MB each (hi, lo)

    float*    e2p      = (float*)d_ws;
    __bf16*   cbh      = (__bf16*)((char*)d_ws + E2_BYTES);
    __bf16*   cblo     = (__bf16*)((char*)d_ws + E2_BYTES + CB_BYTES);
    unsigned* flagcnt  = (unsigned*)((char*)d_ws + E2_BYTES + 2 * CB_BYTES);
    unsigned* flaglist = flagcnt + 16;
    unsigned  flagcap  = (unsigned)((ws_size - (E2_BYTES + 2 * CB_BYTES + 64)) / 4);
    if (flagcap > (unsigned)B) flagcap = (unsigned)B;

    hipLaunchKernelGGL(rvq_prep, dim3(LKD / 8 / 256), dim3(256), 0, stream,
                       codebooks, cbh, cblo, e2p, flagcnt);
    hipLaunchKernelGGL(rvq_mfma, dim3(B / 128), dim3(256), 0, stream,
                       residual, codebooks, cbh, cblo, e2p,
                       flagcnt, flaglist, flagcap, out, B);
    hipLaunchKernelGGL(rvq_fixup, dim3(512), dim3(256), 0, stream,
                       residual, codebooks, e2p, flagcnt, flaglist, flagcap, out, B);
}

// Round 12
// 782.428 us; speedup vs baseline: 5.0504x; 5.0504x over previous
//
#include <hip/hip_runtime.h>
#include <math.h>

// Residual VQ matching a float32 numpy reference (R3/R6/R7/R10-verified):
//   scores = x2 + e2 - 2*(res @ emb.T) in f32, argmin = first-min.
// R12: B-split (Bh via LDS gload_lds, Bl via L2->reg) + 5-BIT index packing:
//   each lane's k = idx5*32 + col (col=lane&31 fixed), so only idx5 (tile*2+sub)
//   is embedded in the score's low-5 mantissa bits (round-to-nearest stomp,
//   perturbation <= ~9e-5) -> margin 6e-4 acc-domain -> ~700 fixup rows.
//   Merged acc per subtile (score = acc directly), time-shared Blr[8] regs,
//   counted vmcnt ladder, setprio around MFMA clusters.
//   Margin-flagged rows -> exact replicated-f32 fixup kernel (R3-verified).

#define D_DIM 128
#define K_CB  1024
#define L_LVL 4
#define LK    (L_LVL * K_CB)
#define LKD   (LK * D_DIM)
#define NT2   16               // 16 tiles x 64 codewords
#define TILE_ELEMS 8192        // 64 cw x 128 dims
#define MARGIN_P5 6e-4f        // acc-domain; covers pack (1.2e-4) + 3-pass err

typedef __bf16 bf16x8 __attribute__((ext_vector_type(8)));
typedef float  f32x16 __attribute__((ext_vector_type(16)));

// force f32 rounding of a product (blocks fma contraction)
static __device__ __forceinline__ float mulr(float a, float b) {
    float p = a * b; asm volatile("" : "+v"(p)); return p;
}

// ---------------- prep: swizzled bf16 hi/lo + pairwise e2 + flag zero ----------------
// chunk j: lane=j&63, kk=(j>>6)&7, s=(j>>9)&1, t=(j>>10)&15, lv=j>>14
// src row = lv*1024 + t*64 + s*32 + (lane&31), elems kk*16 + (lane>>5)*8 + 0..7
__global__ void rvq_prep(const float* __restrict__ cb,
                         __bf16* __restrict__ hi, __bf16* __restrict__ lo,
                         float* __restrict__ e2p, unsigned* __restrict__ flagcnt) {
    int j = blockIdx.x * blockDim.x + threadIdx.x;   // [0, LKD/8)
    if (j == 0) *flagcnt = 0;
    const int lane = j & 63, kk = (j >> 6) & 7, s = (j >> 9) & 1,
              t = (j >> 10) & 15, lv = j >> 14;
    const int row  = lv * K_CB + t * 64 + s * 32 + (lane & 31);
    const int elem = kk * 16 + (lane >> 5) * 8;
    const float* src = cb + (size_t)row * D_DIM + elem;
    float4 a = *(const float4*)src;
    float4 b = *(const float4*)(src + 4);
    float f[8] = {a.x, a.y, a.z, a.w, b.x, b.y, b.z, b.w};
    bf16x8 hv, lvv;
    #pragma unroll
    for (int e = 0; e < 8; ++e) {
        __bf16 h = (__bf16)f[e];
        hv[e]  = h;
        lvv[e] = (__bf16)(f[e] - (float)h);
    }
    *(bf16x8*)(hi + (size_t)j * 8) = hv;
    *(bf16x8*)(lo + (size_t)j * 8) = lvv;

    if (j < LK) {   // numpy-pairwise ||e||^2 for codeword row j
        const float* ep = cb + (size_t)j * D_DIM;
        float r8[8];
        #pragma unroll
        for (int q = 0; q < 8; ++q) r8[q] = mulr(ep[q], ep[q]);
        #pragma unroll
        for (int bb = 1; bb < 16; ++bb)
            #pragma unroll
            for (int q = 0; q < 8; ++q) r8[q] += mulr(ep[bb * 8 + q], ep[bb * 8 + q]);
        e2p[j] = ((r8[0] + r8[1]) + (r8[2] + r8[3])) + ((r8[4] + r8[5]) + (r8[6] + r8[7]));
    }
}

// ---------------- stage one 64-cw tile's hi into LDS (linear, coalesced) ----------------
static __device__ __forceinline__ void stage_tile(
    const __bf16* srcTile, __bf16* dst, int wave, int lane) {
    #pragma unroll
    for (int c = 0; c < 4; ++c) {
        const int it = wave * 4 + c;   // 1KB chunk id, 0..15
        __builtin_amdgcn_global_load_lds(
            (const __attribute__((address_space(1))) void*)(srcTile + it * 512 + lane * 8),
            (__attribute__((address_space(3))) void*)(dst + it * 512), 16, 0, 0);
    }
}

#define MFMA(A, Bv, C) __builtin_amdgcn_mfma_f32_32x32x16_bf16(A, Bv, C, 0, 0, 0)

// pack idx5 into low-5 mantissa bits, round-to-nearest stomp
static __device__ __forceinline__ float pack5(float sc, unsigned pk5) {
    unsigned u = __float_as_uint(sc);
    return __uint_as_float(((u + 16u) & ~31u) | pk5);
}

// ---------------- MFMA hot kernel ----------------
__global__ __launch_bounds__(256)
void rvq_mfma(const float* __restrict__ residual,
              const float* __restrict__ codebooks,
              const __bf16* __restrict__ cbh, const __bf16* __restrict__ cbl,
              const float* __restrict__ e2p,
              unsigned* __restrict__ flagcnt, unsigned* __restrict__ flaglist,
              unsigned flagcap, float* __restrict__ out, int B) {
    __shared__ __align__(16) __bf16 bufh[2][TILE_ELEMS];   // 2 x 16 KB
    __shared__ float e2s[K_CB];                            // 4 KB
    __shared__ int   bidxs[L_LVL][128];
    __shared__ unsigned char flg[128];

    const int tid  = threadIdx.x;
    const int wave = tid >> 6;
    const int lane = tid & 63;
    const int col  = lane & 31;
    const int h    = lane >> 5;
    const int rb   = wave * 32;
    const int grow = blockIdx.x * 128 + rb + col;

    if (tid < 128) flg[tid] = 0;

    // A fragments: residual row split to bf16 hi/lo, in registers.
    bf16x8 Ah[8], Al[8];
    {
        const float* rowp = residual + (size_t)grow * D_DIM;
        #pragma unroll
        for (int kk = 0; kk < 8; ++kk) {
            const int d0 = kk * 16 + h * 8;
            float4 a = *(const float4*)(rowp + d0);
            float4 b = *(const float4*)(rowp + d0 + 4);
            float f[8] = {a.x, a.y, a.z, a.w, b.x, b.y, b.z, b.w};
            #pragma unroll
            for (int e = 0; e < 8; ++e) {
                __bf16 hh = (__bf16)f[e];
                Ah[kk][e] = hh;
                Al[kk][e] = (__bf16)(f[e] - (float)hh);
            }
        }
    }

    for (int l = 0; l < L_LVL; ++l) {
        const __bf16* cbhL = cbh + (size_t)l * NT2 * TILE_ELEMS;
        const __bf16* cblL = cbl + (size_t)l * NT2 * TILE_ELEMS;

        // level's e2 -> LDS, drain all stray vmem (gathers/A-build)
        ((float4*)e2s)[tid] = ((const float4*)(e2p + l * K_CB))[tid];
        asm volatile("s_waitcnt vmcnt(0)" ::: "memory");

        // packed top-2 (real packed scores are >= ~2; 0 is safe -inf)
        float rbest[16], rbest2[16];
        #pragma unroll
        for (int s = 0; s < 16; ++s) { rbest[s] = 0.f; rbest2[s] = 0.f; }

        stage_tile(cbhL + 0 * TILE_ELEMS, &bufh[0][0], wave, lane);
        stage_tile(cbhL + 1 * TILE_ELEMS, &bufh[1][0], wave, lane);

        for (int t = 0; t < NT2; ++t) {
            const int cur = t & 1;
            const __bf16* bh  = &bufh[cur][0];
            const __bf16* blT = cblL + (size_t)t * TILE_ELEMS;

            if (t == 0) asm volatile("s_waitcnt vmcnt(4) lgkmcnt(0)" ::: "memory");
            __builtin_amdgcn_s_barrier();      // tile t resident; e2s visible
            __builtin_amdgcn_sched_barrier(0);

            // issue Bl0 (subtile0 lo) early; lands under the 32 Bh MFMAs
            bf16x8 Blr[8];
            #pragma unroll
            for (int kk = 0; kk < 8; ++kk)
                Blr[kk] = *(const bf16x8*)(blT + kk * 512 + lane * 8);

            // acc init folds e2 and +16 offset: packed score = acc_final
            const float e2i0 = fmaf(-0.5f, e2s[t * 64 + col], 16.f);
            const float e2i1 = fmaf(-0.5f, e2s[t * 64 + 32 + col], 16.f);
            f32x16 acc0, acc1;
            #pragma unroll
            for (int s = 0; s < 16; ++s) { acc0[s] = e2i0; acc1[s] = e2i1; }

            __builtin_amdgcn_s_setprio(1);
            #pragma unroll
            for (int kk = 0; kk < 8; ++kk) {   // Bh passes, 2 chains interleaved
                bf16x8 Bh0 = *(const bf16x8*)(bh + kk * 512 + lane * 8);
                bf16x8 Bh1 = *(const bf16x8*)(bh + 4096 + kk * 512 + lane * 8);
                acc0 = MFMA(Ah[kk], Bh0, acc0);
                acc0 = MFMA(Al[kk], Bh0, acc0);
                acc1 = MFMA(Ah[kk], Bh1, acc1);
                acc1 = MFMA(Al[kk], Bh1, acc1);
            }
            // Bl0 landed (also drains stage(t+1), issued >1 iteration ago)
            asm volatile("s_waitcnt vmcnt(0)" ::: "memory");
            __builtin_amdgcn_sched_barrier(0);
            #pragma unroll
            for (int kk = 0; kk < 8; ++kk) acc0 = MFMA(Ah[kk], Blr[kk], acc0);
            __builtin_amdgcn_s_setprio(0);

            // reload Blr with subtile1 lo (reuses regs; hidden under
            // barrier + stage issue + subtile0 scoring)
            #pragma unroll
            for (int kk = 0; kk < 8; ++kk)
                Blr[kk] = *(const bf16x8*)(blT + 4096 + kk * 512 + lane * 8);

            __builtin_amdgcn_sched_barrier(0);
            __builtin_amdgcn_s_barrier();      // all waves done reading bufh[cur]
            asm volatile("" ::: "memory");
            if (t + 2 < NT2)
                stage_tile(cbhL + (size_t)(t + 2) * TILE_ELEMS, &bufh[cur][0], wave, lane);

            // subtile0 top-2 while Bl1 in flight
            const unsigned pk0 = 31u - (unsigned)(t * 2);
            #pragma unroll
            for (int s = 0; s < 16; ++s) {
                float p0 = pack5(acc0[s], pk0);
                rbest2[s] = __builtin_amdgcn_fmed3f(p0, rbest[s], rbest2[s]);
                rbest[s]  = fmaxf(rbest[s], p0);
            }

            // Bl1 landed; stage(t+2)'s 4 stay in flight (counted)
            if (t + 2 < NT2) asm volatile("s_waitcnt vmcnt(4)" ::: "memory");
            else             asm volatile("s_waitcnt vmcnt(0)" ::: "memory");
            __builtin_amdgcn_sched_barrier(0);
            __builtin_amdgcn_s_setprio(1);
            #pragma unroll
            for (int kk = 0; kk < 8; ++kk) acc1 = MFMA(Ah[kk], Blr[kk], acc1);
            __builtin_amdgcn_s_setprio(0);

            const unsigned pk1 = 31u - (unsigned)(t * 2 + 1);
            #pragma unroll
            for (int s = 0; s < 16; ++s) {
                float p1 = pack5(acc1[s], pk1);
                rbest2[s] = __builtin_amdgcn_fmed3f(p1, rbest[s], rbest2[s]);
                rbest[s]  = fmaxf(rbest[s], p1);
            }
        }

        // merge across the 32 cols: packed value (score+idx5) + explicit col.
        // higher packed = better score, then lower idx5; equal packed -> lower col.
        #pragma unroll
        for (int s = 0; s < 16; ++s) {
            float b = rbest[s], b2 = rbest2[s];
            int   c = col;
            #pragma unroll
            for (int m = 1; m <= 16; m <<= 1) {
                float bo  = __shfl_xor(b,  m, 64);
                float b2o = __shfl_xor(b2, m, 64);
                int   co  = __shfl_xor(c,  m, 64);
                float nb2 = fmaxf(fminf(b, bo), fmaxf(b2, b2o));
                if (bo > b || (bo == b && co < c)) { b = bo; c = co; }
                b2 = nb2;
            }
            const int rloc = (s & 3) + 8 * (s >> 2) + 4 * h;   // verified C row map
            if (col == 0) {
                int idx5 = 31 - (int)(__float_as_uint(b) & 31u);
                bidxs[l][rb + rloc] = idx5 * 32 + c;
                if (b - b2 <= MARGIN_P5) flg[rb + rloc] = 1;
            }
        }
        __syncthreads();

        // residual update in f32 from exact codebook, re-split to bf16 pair
        {
            const int bi = bidxs[l][rb + col];
            const float* qp = codebooks + ((size_t)l * K_CB + bi) * D_DIM;
            #pragma unroll
            for (int kk = 0; kk < 8; ++kk) {
                const int d0 = kk * 16 + h * 8;
                float4 qa = *(const float4*)(qp + d0);
                float4 qb = *(const float4*)(qp + d0 + 4);
                float q[8] = {qa.x, qa.y, qa.z, qa.w, qb.x, qb.y, qb.z, qb.w};
                #pragma unroll
                for (int e = 0; e < 8; ++e) {
                    float r = ((float)Ah[kk][e] + (float)Al[kk][e]) - q[e];
                    __bf16 hh = (__bf16)r;
                    Ah[kk][e] = hh;
                    Al[kk][e] = (__bf16)(r - (float)hh);
                }
            }
        }
    }

    // quantized = r0 - r_final
    {
        const float* rowp = residual + (size_t)grow * D_DIM;
        float* op = out + (size_t)grow * D_DIM;
        #pragma unroll
        for (int kk = 0; kk < 8; ++kk) {
            const int d0 = kk * 16 + h * 8;
            float4 a = *(const float4*)(rowp + d0);
            float4 b = *(const float4*)(rowp + d0 + 4);
            float f[8] = {a.x, a.y, a.z, a.w, b.x, b.y, b.z, b.w};
            float o[8];
            #pragma unroll
            for (int e = 0; e < 8; ++e)
                o[e] = f[e] - ((float)Ah[kk][e] + (float)Al[kk][e]);
            *(float4*)(op + d0)     = make_float4(o[0], o[1], o[2], o[3]);
            *(float4*)(op + d0 + 4) = make_float4(o[4], o[5], o[6], o[7]);
        }
    }
    if (tid < 128) {
        int row = blockIdx.x * 128 + tid;
        float4* cp = (float4*)(out + (size_t)B * D_DIM + (size_t)row * L_LVL);
        *cp = make_float4((float)bidxs[0][tid], (float)bidxs[1][tid],
                          (float)bidxs[2][tid], (float)bidxs[3][tid]);
        if (flg[tid]) {
            unsigned pos = atomicAdd(flagcnt, 1u);
            if (pos < flagcap) flaglist[pos] = row;
        }
    }
}

// ---------------- fixup: replicated reference semantics per flagged row ----------------
__global__ __launch_bounds__(256, 1)
void rvq_fixup(const float* __restrict__ residual,
               const float* __restrict__ codebooks,
               const float* __restrict__ e2p,
               const unsigned* __restrict__ flagcnt,
               const unsigned* __restrict__ flaglist,
               unsigned flagcap, float* __restrict__ out, int B) {
    __shared__ float rbuf[D_DIM];
    __shared__ float r0buf[D_DIM];
    __shared__ float x2s;
    __shared__ float redS[256];
    __shared__ int   redK[256];
    __shared__ int   codes_s[L_LVL];

    unsigned n = *flagcnt;
    if (n > flagcap) n = flagcap;

    for (unsigned b = blockIdx.x; b < n; b += gridDim.x) {
        int row = (int)flaglist[b];
        if (threadIdx.x < 32) {
            float4 v = ((const float4*)(residual + (size_t)row * D_DIM))[threadIdx.x];
            *(float4*)&rbuf[threadIdx.x * 4]  = v;
            *(float4*)&r0buf[threadIdx.x * 4] = v;
        }
        __syncthreads();

        for (int l = 0; l < L_LVL; ++l) {
            const float* cbl = codebooks + (size_t)l * K_CB * D_DIM;
            if (threadIdx.x == 0) {
                float r8[8];
                #pragma unroll
                for (int q = 0; q < 8; ++q) r8[q] = mulr(rbuf[q], rbuf[q]);
                for (int bb = 1; bb < 16; ++bb)
                    #pragma unroll
                    for (int q = 0; q < 8; ++q) r8[q] += mulr(rbuf[bb * 8 + q], rbuf[bb * 8 + q]);
                x2s = ((r8[0] + r8[1]) + (r8[2] + r8[3])) + ((r8[4] + r8[5]) + (r8[6] + r8[7]));
            }
            __syncthreads();
            float x2 = x2s;

            float bS = 3.4e38f;
            int   bK = 0x7fffffff;
            for (int m = 0; m < 4; ++m) {
                int k = threadIdx.x + m * 256;
                const float4* ek = (const float4*)(cbl + (size_t)k * D_DIM);
                double dd = 0.0;
                for (int c = 0; c < 32; ++c) {
                    float4 v = ek[c];
                    dd = fma((double)v.x, (double)rbuf[c * 4 + 0], dd);
                    dd = fma((double)v.y, (double)rbuf[c * 4 + 1], dd);
                    dd = fma((double)v.z, (double)rbuf[c * 4 + 2], dd);
                    dd = fma((double)v.w, (double)rbuf[c * 4 + 3], dd);
                }
                float M = (float)dd;                 // fl32(exact dot)
                float A = x2 + e2p[l * K_CB + k];    // fl32(x2 + e2)
                float S = A - 2.0f * M;              // final f32 rounding
                if (S < bS || (S == bS && k < bK)) { bS = S; bK = k; }
            }
            redS[threadIdx.x] = bS; redK[threadIdx.x] = bK;
            __syncthreads();
            for (int s = 128; s > 0; s >>= 1) {
                if (threadIdx.x < (unsigned)s) {
                    float So = redS[threadIdx.x + s];
                    int   Ko = redK[threadIdx.x + s];
                    if (So < redS[threadIdx.x] ||
                        (So == redS[threadIdx.x] && Ko < redK[threadIdx.x])) {
                        redS[threadIdx.x] = So; redK[threadIdx.x] = Ko;
                    }
                }
                __syncthreads();
            }
            int bi = redK[0];
            if (threadIdx.x == 0) codes_s[l] = bi;
            if (threadIdx.x < 32) {
                float4 q = ((const float4*)(cbl + (size_t)bi * D_DIM))[threadIdx.x];
                float4* p = (float4*)&rbuf[threadIdx.x * 4];
                float4 x = *p;
                x.x -= q.x; x.y -= q.y; x.z -= q.z; x.w -= q.w;
                *p = x;
            }
            __syncthreads();
        }

        if (threadIdx.x < 32) {
            float4 a = *(float4*)&r0buf[threadIdx.x * 4];
            float4 r = *(float4*)&rbuf[threadIdx.x * 4];
            ((float4*)(out + (size_t)row * D_DIM))[threadIdx.x] =
                make_float4(a.x - r.x, a.y - r.y, a.z - r.z, a.w - r.w);
        }
        if (threadIdx.x == 0) {
            float4* cp = (float4*)(out + (size_t)B * D_DIM + (size_t)row * L_LVL);
            *cp = make_float4((float)codes_s[0], (float)codes_s[1],
                              (float)codes_s[2], (float)codes_s[3]);
        }
        __syncthreads();
    }
}

extern "C" void kernel_launch(void* const* d_in, const int* in_sizes, int n_in,
                              void* d_out, int out_size, void* d_ws, size_t ws_size,
                              hipStream_t stream) {
    const float* residual  = (const float*)d_in[0];
    const float* codebooks = (const float*)d_in[1];
    float* out = (float*)d_out;
    int B = in_sizes[0] / D_DIM;  // 131072

    const size_t E2_BYTES = LK * sizeof(float);          // 16 KB
    const size_t CB_BYTES = (size_t)LKD * 2;             // 1 MB each (hi, lo)

    float*    e2p      = (float*)d_ws;
    __bf16*   cbh      = (__bf16*)((char*)d_ws + E2_BYTES);
    __bf16*   cblo     = (__bf16*)((char*)d_ws + E2_BYTES + CB_BYTES);
    unsigned* flagcnt  = (unsigned*)((char*)d_ws + E2_BYTES + 2 * CB_BYTES);
    unsigned* flaglist = flagcnt + 16;
    unsigned  flagcap  = (unsigned)((ws_size - (E2_BYTES + 2 * CB_BYTES + 64)) / 4);
    if (flagcap > (unsigned)B) flagcap = (unsigned)B;

    hipLaunchKernelGGL(rvq_prep, dim3(LKD / 8 / 256), dim3(256), 0, stream,
                       codebooks, cbh, cblo, e2p, flagcnt);
    hipLaunchKernelGGL(rvq_mfma, dim3(B / 128), dim3(256), 0, stream,
                       residual, codebooks, cbh, cblo, e2p,
                       flagcnt, flaglist, flagcap, out, B);
    hipLaunchKernelGGL(rvq_fixup, dim3(512), dim3(256), 0, stream,
                       residual, codebooks, e2p, flagcnt, flaglist, flagcap, out, B);
}

// Round 13
// 764.644 us; speedup vs baseline: 5.1679x; 1.0233x over previous
//
#include <hip/hip_runtime.h>
#include <math.h>

// Residual VQ matching a float32 numpy reference (R3/R6/R7/R10/R12-verified):
//   scores = x2 + e2 - 2*(res @ emb.T) in f32, argmin = first-min.
// R13: R12 hot kernel (B-split: Bh via LDS gload_lds, Bl via L2->reg; 5-bit
// index packing into score mantissa; counted vmcnt; setprio) unchanged except
// launch_bounds(256,3). Fixup made ~4x faster (4 independent f64 chains,
// grid 1024) and margin tightened 6e-4 -> 4.5e-4 (= proven 1.25e-4 true-error
// margin + 1.8e-4 deterministic pack bound + slack).

#define D_DIM 128
#define K_CB  1024
#define L_LVL 4
#define LK    (L_LVL * K_CB)
#define LKD   (LK * D_DIM)
#define NT2   16               // 16 tiles x 64 codewords
#define TILE_ELEMS 8192        // 64 cw x 128 dims
#define MARGIN_P5 4.5e-4f      // acc-domain; 1.25e-4 proven + 1.8e-4 pack + slack

typedef __bf16 bf16x8 __attribute__((ext_vector_type(8)));
typedef float  f32x16 __attribute__((ext_vector_type(16)));

// force f32 rounding of a product (blocks fma contraction)
static __device__ __forceinline__ float mulr(float a, float b) {
    float p = a * b; asm volatile("" : "+v"(p)); return p;
}

// ---------------- prep: swizzled bf16 hi/lo + pairwise e2 + flag zero ----------------
// chunk j: lane=j&63, kk=(j>>6)&7, s=(j>>9)&1, t=(j>>10)&15, lv=j>>14
// src row = lv*1024 + t*64 + s*32 + (lane&31), elems kk*16 + (lane>>5)*8 + 0..7
__global__ void rvq_prep(const float* __restrict__ cb,
                         __bf16* __restrict__ hi, __bf16* __restrict__ lo,
                         float* __restrict__ e2p, unsigned* __restrict__ flagcnt) {
    int j = blockIdx.x * blockDim.x + threadIdx.x;   // [0, LKD/8)
    if (j == 0) *flagcnt = 0;
    const int lane = j & 63, kk = (j >> 6) & 7, s = (j >> 9) & 1,
              t = (j >> 10) & 15, lv = j >> 14;
    const int row  = lv * K_CB + t * 64 + s * 32 + (lane & 31);
    const int elem = kk * 16 + (lane >> 5) * 8;
    const float* src = cb + (size_t)row * D_DIM + elem;
    float4 a = *(const float4*)src;
    float4 b = *(const float4*)(src + 4);
    float f[8] = {a.x, a.y, a.z, a.w, b.x, b.y, b.z, b.w};
    bf16x8 hv, lvv;
    #pragma unroll
    for (int e = 0; e < 8; ++e) {
        __bf16 h = (__bf16)f[e];
        hv[e]  = h;
        lvv[e] = (__bf16)(f[e] - (float)h);
    }
    *(bf16x8*)(hi + (size_t)j * 8) = hv;
    *(bf16x8*)(lo + (size_t)j * 8) = lvv;

    if (j < LK) {   // numpy-pairwise ||e||^2 for codeword row j
        const float* ep = cb + (size_t)j * D_DIM;
        float r8[8];
        #pragma unroll
        for (int q = 0; q < 8; ++q) r8[q] = mulr(ep[q], ep[q]);
        #pragma unroll
        for (int bb = 1; bb < 16; ++bb)
            #pragma unroll
            for (int q = 0; q < 8; ++q) r8[q] += mulr(ep[bb * 8 + q], ep[bb * 8 + q]);
        e2p[j] = ((r8[0] + r8[1]) + (r8[2] + r8[3])) + ((r8[4] + r8[5]) + (r8[6] + r8[7]));
    }
}

// ---------------- stage one 64-cw tile's hi into LDS (linear, coalesced) ----------------
static __device__ __forceinline__ void stage_tile(
    const __bf16* srcTile, __bf16* dst, int wave, int lane) {
    #pragma unroll
    for (int c = 0; c < 4; ++c) {
        const int it = wave * 4 + c;   // 1KB chunk id, 0..15
        __builtin_amdgcn_global_load_lds(
            (const __attribute__((address_space(1))) void*)(srcTile + it * 512 + lane * 8),
            (__attribute__((address_space(3))) void*)(dst + it * 512), 16, 0, 0);
    }
}

#define MFMA(A, Bv, C) __builtin_amdgcn_mfma_f32_32x32x16_bf16(A, Bv, C, 0, 0, 0)

// pack idx5 into low-5 mantissa bits, round-to-nearest stomp
static __device__ __forceinline__ float pack5(float sc, unsigned pk5) {
    unsigned u = __float_as_uint(sc);
    return __uint_as_float(((u + 16u) & ~31u) | pk5);
}

// ---------------- MFMA hot kernel ----------------
__global__ __launch_bounds__(256, 3)
void rvq_mfma(const float* __restrict__ residual,
              const float* __restrict__ codebooks,
              const __bf16* __restrict__ cbh, const __bf16* __restrict__ cbl,
              const float* __restrict__ e2p,
              unsigned* __restrict__ flagcnt, unsigned* __restrict__ flaglist,
              unsigned flagcap, float* __restrict__ out, int B) {
    __shared__ __align__(16) __bf16 bufh[2][TILE_ELEMS];   // 2 x 16 KB
    __shared__ float e2s[K_CB];                            // 4 KB
    __shared__ int   bidxs[L_LVL][128];
    __shared__ unsigned char flg[128];

    const int tid  = threadIdx.x;
    const int wave = tid >> 6;
    const int lane = tid & 63;
    const int col  = lane & 31;
    const int h    = lane >> 5;
    const int rb   = wave * 32;
    const int grow = blockIdx.x * 128 + rb + col;

    if (tid < 128) flg[tid] = 0;

    // A fragments: residual row split to bf16 hi/lo, in registers.
    bf16x8 Ah[8], Al[8];
    {
        const float* rowp = residual + (size_t)grow * D_DIM;
        #pragma unroll
        for (int kk = 0; kk < 8; ++kk) {
            const int d0 = kk * 16 + h * 8;
            float4 a = *(const float4*)(rowp + d0);
            float4 b = *(const float4*)(rowp + d0 + 4);
            float f[8] = {a.x, a.y, a.z, a.w, b.x, b.y, b.z, b.w};
            #pragma unroll
            for (int e = 0; e < 8; ++e) {
                __bf16 hh = (__bf16)f[e];
                Ah[kk][e] = hh;
                Al[kk][e] = (__bf16)(f[e] - (float)hh);
            }
        }
    }

    for (int l = 0; l < L_LVL; ++l) {
        const __bf16* cbhL = cbh + (size_t)l * NT2 * TILE_ELEMS;
        const __bf16* cblL = cbl + (size_t)l * NT2 * TILE_ELEMS;

        // level's e2 -> LDS, drain all stray vmem (gathers/A-build)
        ((float4*)e2s)[tid] = ((const float4*)(e2p + l * K_CB))[tid];
        asm volatile("s_waitcnt vmcnt(0)" ::: "memory");

        // packed top-2 (real packed scores are >= ~2; 0 is safe -inf)
        float rbest[16], rbest2[16];
        #pragma unroll
        for (int s = 0; s < 16; ++s) { rbest[s] = 0.f; rbest2[s] = 0.f; }

        stage_tile(cbhL + 0 * TILE_ELEMS, &bufh[0][0], wave, lane);
        stage_tile(cbhL + 1 * TILE_ELEMS, &bufh[1][0], wave, lane);

        for (int t = 0; t < NT2; ++t) {
            const int cur = t & 1;
            const __bf16* bh  = &bufh[cur][0];
            const __bf16* blT = cblL + (size_t)t * TILE_ELEMS;

            if (t == 0) asm volatile("s_waitcnt vmcnt(4) lgkmcnt(0)" ::: "memory");
            __builtin_amdgcn_s_barrier();      // tile t resident; e2s visible
            __builtin_amdgcn_sched_barrier(0);

            // issue Bl0 (subtile0 lo) early; lands under the 32 Bh MFMAs
            bf16x8 Blr[8];
            #pragma unroll
            for (int kk = 0; kk < 8; ++kk)
                Blr[kk] = *(const bf16x8*)(blT + kk * 512 + lane * 8);

            // acc init folds e2 and +16 offset: packed score = acc_final
            const float e2i0 = fmaf(-0.5f, e2s[t * 64 + col], 16.f);
            const float e2i1 = fmaf(-0.5f, e2s[t * 64 + 32 + col], 16.f);
            f32x16 acc0, acc1;
            #pragma unroll
            for (int s = 0; s < 16; ++s) { acc0[s] = e2i0; acc1[s] = e2i1; }

            __builtin_amdgcn_s_setprio(1);
            #pragma unroll
            for (int kk = 0; kk < 8; ++kk) {   // Bh passes, 2 chains interleaved
                bf16x8 Bh0 = *(const bf16x8*)(bh + kk * 512 + lane * 8);
                bf16x8 Bh1 = *(const bf16x8*)(bh + 4096 + kk * 512 + lane * 8);
                acc0 = MFMA(Ah[kk], Bh0, acc0);
                acc0 = MFMA(Al[kk], Bh0, acc0);
                acc1 = MFMA(Ah[kk], Bh1, acc1);
                acc1 = MFMA(Al[kk], Bh1, acc1);
            }
            // Bl0 landed (also drains stage(t+1), issued >1 iteration ago)
            asm volatile("s_waitcnt vmcnt(0)" ::: "memory");
            __builtin_amdgcn_sched_barrier(0);
            #pragma unroll
            for (int kk = 0; kk < 8; ++kk) acc0 = MFMA(Ah[kk], Blr[kk], acc0);
            __builtin_amdgcn_s_setprio(0);

            // reload Blr with subtile1 lo (reuses regs; hidden under
            // barrier + stage issue + subtile0 scoring)
            #pragma unroll
            for (int kk = 0; kk < 8; ++kk)
                Blr[kk] = *(const bf16x8*)(blT + 4096 + kk * 512 + lane * 8);

            __builtin_amdgcn_sched_barrier(0);
            __builtin_amdgcn_s_barrier();      // all waves done reading bufh[cur]
            asm volatile("" ::: "memory");
            if (t + 2 < NT2)
                stage_tile(cbhL + (size_t)(t + 2) * TILE_ELEMS, &bufh[cur][0], wave, lane);

            // subtile0 top-2 while Bl1 in flight
            const unsigned pk0 = 31u - (unsigned)(t * 2);
            #pragma unroll
            for (int s = 0; s < 16; ++s) {
                float p0 = pack5(acc0[s], pk0);
                rbest2[s] = __builtin_amdgcn_fmed3f(p0, rbest[s], rbest2[s]);
                rbest[s]  = fmaxf(rbest[s], p0);
            }

            // Bl1 landed; stage(t+2)'s 4 stay in flight (counted)
            if (t + 2 < NT2) asm volatile("s_waitcnt vmcnt(4)" ::: "memory");
            else             asm volatile("s_waitcnt vmcnt(0)" ::: "memory");
            __builtin_amdgcn_sched_barrier(0);
            __builtin_amdgcn_s_setprio(1);
            #pragma unroll
            for (int kk = 0; kk < 8; ++kk) acc1 = MFMA(Ah[kk], Blr[kk], acc1);
            __builtin_amdgcn_s_setprio(0);

            const unsigned pk1 = 31u - (unsigned)(t * 2 + 1);
            #pragma unroll
            for (int s = 0; s < 16; ++s) {
                float p1 = pack5(acc1[s], pk1);
                rbest2[s] = __builtin_amdgcn_fmed3f(p1, rbest[s], rbest2[s]);
                rbest[s]  = fmaxf(rbest[s], p1);
            }
        }

        // merge across the 32 cols: packed value (score+idx5) + explicit col.
        // higher packed = better score, then lower idx5; equal packed -> lower col.
        #pragma unroll
        for (int s = 0; s < 16; ++s) {
            float b = rbest[s], b2 = rbest2[s];
            int   c = col;
            #pragma unroll
            for (int m = 1; m <= 16; m <<= 1) {
                float bo  = __shfl_xor(b,  m, 64);
                float b2o = __shfl_xor(b2, m, 64);
                int   co  = __shfl_xor(c,  m, 64);
                float nb2 = fmaxf(fminf(b, bo), fmaxf(b2, b2o));
                if (bo > b || (bo == b && co < c)) { b = bo; c = co; }
                b2 = nb2;
            }
            const int rloc = (s & 3) + 8 * (s >> 2) + 4 * h;   // verified C row map
            if (col == 0) {
                int idx5 = 31 - (int)(__float_as_uint(b) & 31u);
                bidxs[l][rb + rloc] = idx5 * 32 + c;
                if (b - b2 <= MARGIN_P5) flg[rb + rloc] = 1;
            }
        }
        __syncthreads();

        // residual update in f32 from exact codebook, re-split to bf16 pair
        {
            const int bi = bidxs[l][rb + col];
            const float* qp = codebooks + ((size_t)l * K_CB + bi) * D_DIM;
            #pragma unroll
            for (int kk = 0; kk < 8; ++kk) {
                const int d0 = kk * 16 + h * 8;
                float4 qa = *(const float4*)(qp + d0);
                float4 qb = *(const float4*)(qp + d0 + 4);
                float q[8] = {qa.x, qa.y, qa.z, qa.w, qb.x, qb.y, qb.z, qb.w};
                #pragma unroll
                for (int e = 0; e < 8; ++e) {
                    float r = ((float)Ah[kk][e] + (float)Al[kk][e]) - q[e];
                    __bf16 hh = (__bf16)r;
                    Ah[kk][e] = hh;
                    Al[kk][e] = (__bf16)(r - (float)hh);
                }
            }
        }
    }

    // quantized = r0 - r_final
    {
        const float* rowp = residual + (size_t)grow * D_DIM;
        float* op = out + (size_t)grow * D_DIM;
        #pragma unroll
        for (int kk = 0; kk < 8; ++kk) {
            const int d0 = kk * 16 + h * 8;
            float4 a = *(const float4*)(rowp + d0);
            float4 b = *(const float4*)(rowp + d0 + 4);
            float f[8] = {a.x, a.y, a.z, a.w, b.x, b.y, b.z, b.w};
            float o[8];
            #pragma unroll
            for (int e = 0; e < 8; ++e)
                o[e] = f[e] - ((float)Ah[kk][e] + (float)Al[kk][e]);
            *(float4*)(op + d0)     = make_float4(o[0], o[1], o[2], o[3]);
            *(float4*)(op + d0 + 4) = make_float4(o[4], o[5], o[6], o[7]);
        }
    }
    if (tid < 128) {
        int row = blockIdx.x * 128 + tid;
        float4* cp = (float4*)(out + (size_t)B * D_DIM + (size_t)row * L_LVL);
        *cp = make_float4((float)bidxs[0][tid], (float)bidxs[1][tid],
                          (float)bidxs[2][tid], (float)bidxs[3][tid]);
        if (flg[tid]) {
            unsigned pos = atomicAdd(flagcnt, 1u);
            if (pos < flagcap) flaglist[pos] = row;
        }
    }
}

// ---------------- fixup: replicated reference semantics per flagged row ----------------
__global__ __launch_bounds__(256, 1)
void rvq_fixup(const float* __restrict__ residual,
               const float* __restrict__ codebooks,
               const float* __restrict__ e2p,
               const unsigned* __restrict__ flagcnt,
               const unsigned* __restrict__ flaglist,
               unsigned flagcap, float* __restrict__ out, int B) {
    __shared__ float rbuf[D_DIM];
    __shared__ float r0buf[D_DIM];
    __shared__ float x2s;
    __shared__ float redS[256];
    __shared__ int   redK[256];
    __shared__ int   codes_s[L_LVL];

    unsigned n = *flagcnt;
    if (n > flagcap) n = flagcap;

    for (unsigned b = blockIdx.x; b < n; b += gridDim.x) {
        int row = (int)flaglist[b];
        if (threadIdx.x < 32) {
            float4 v = ((const float4*)(residual + (size_t)row * D_DIM))[threadIdx.x];
            *(float4*)&rbuf[threadIdx.x * 4]  = v;
            *(float4*)&r0buf[threadIdx.x * 4] = v;
        }
        __syncthreads();

        for (int l = 0; l < L_LVL; ++l) {
            const float* cbl = codebooks + (size_t)l * K_CB * D_DIM;
            if (threadIdx.x == 0) {
                float r8[8];
                #pragma unroll
                for (int q = 0; q < 8; ++q) r8[q] = mulr(rbuf[q], rbuf[q]);
                for (int bb = 1; bb < 16; ++bb)
                    #pragma unroll
                    for (int q = 0; q < 8; ++q) r8[q] += mulr(rbuf[bb * 8 + q], rbuf[bb * 8 + q]);
                x2s = ((r8[0] + r8[1]) + (r8[2] + r8[3])) + ((r8[4] + r8[5]) + (r8[6] + r8[7]));
            }
            __syncthreads();
            float x2 = x2s;

            float bS = 3.4e38f;
            int   bK = 0x7fffffff;
            for (int m = 0; m < 4; ++m) {
                int k = threadIdx.x + m * 256;
                const float4* ek = (const float4*)(cbl + (size_t)k * D_DIM);
                // 4 independent f64 chains (reorder noise ~2^-50 << f32 ulp)
                double dd0 = 0.0, dd1 = 0.0, dd2 = 0.0, dd3 = 0.0;
                for (int c = 0; c < 32; c += 4) {
                    float4 v0 = ek[c], v1 = ek[c + 1], v2 = ek[c + 2], v3 = ek[c + 3];
                    dd0 = fma((double)v0.x, (double)rbuf[c * 4 + 0], dd0);
                    dd0 = fma((double)v0.y, (double)rbuf[c * 4 + 1], dd0);
                    dd0 = fma((double)v0.z, (double)rbuf[c * 4 + 2], dd0);
                    dd0 = fma((double)v0.w, (double)rbuf[c * 4 + 3], dd0);
                    dd1 = fma((double)v1.x, (double)rbuf[c * 4 + 4], dd1);
                    dd1 = fma((double)v1.y, (double)rbuf[c * 4 + 5], dd1);
                    dd1 = fma((double)v1.z, (double)rbuf[c * 4 + 6], dd1);
                    dd1 = fma((double)v1.w, (double)rbuf[c * 4 + 7], dd1);
                    dd2 = fma((double)v2.x, (double)rbuf[c * 4 + 8], dd2);
                    dd2 = fma((double)v2.y, (double)rbuf[c * 4 + 9], dd2);
                    dd2 = fma((double)v2.z, (double)rbuf[c * 4 + 10], dd2);
                    dd2 = fma((double)v2.w, (double)rbuf[c * 4 + 11], dd2);
                    dd3 = fma((double)v3.x, (double)rbuf[c * 4 + 12], dd3);
                    dd3 = fma((double)v3.y, (double)rbuf[c * 4 + 13], dd3);
                    dd3 = fma((double)v3.z, (double)rbuf[c * 4 + 14], dd3);
                    dd3 = fma((double)v3.w, (double)rbuf[c * 4 + 15], dd3);
                }
                float M = (float)((dd0 + dd1) + (dd2 + dd3));  // fl32(exact dot)
                float A = x2 + e2p[l * K_CB + k];    // fl32(x2 + e2)
                float S = A - 2.0f * M;              // final f32 rounding
                if (S < bS || (S == bS && k < bK)) { bS = S; bK = k; }
            }
            redS[threadIdx.x] = bS; redK[threadIdx.x] = bK;
            __syncthreads();
            for (int s = 128; s > 0; s >>= 1) {
                if (threadIdx.x < (unsigned)s) {
                    float So = redS[threadIdx.x + s];
                    int   Ko = redK[threadIdx.x + s];
                    if (So < redS[threadIdx.x] ||
                        (So == redS[threadIdx.x] && Ko < redK[threadIdx.x])) {
                        redS[threadIdx.x] = So; redK[threadIdx.x] = Ko;
                    }
                }
                __syncthreads();
            }
            int bi = redK[0];
            if (threadIdx.x == 0) codes_s[l] = bi;
            if (threadIdx.x < 32) {
                float4 q = ((const float4*)(cbl + (size_t)bi * D_DIM))[threadIdx.x];
                float4* p = (float4*)&rbuf[threadIdx.x * 4];
                float4 x = *p;
                x.x -= q.x; x.y -= q.y; x.z -= q.z; x.w -= q.w;
                *p = x;
            }
            __syncthreads();
        }

        if (threadIdx.x < 32) {
            float4 a = *(float4*)&r0buf[threadIdx.x * 4];
            float4 r = *(float4*)&rbuf[threadIdx.x * 4];
            ((float4*)(out + (size_t)row * D_DIM))[threadIdx.x] =
                make_float4(a.x - r.x, a.y - r.y, a.z - r.z, a.w - r.w);
        }
        if (threadIdx.x == 0) {
            float4* cp = (float4*)(out + (size_t)B * D_DIM + (size_t)row * L_LVL);
            *cp = make_float4((float)codes_s[0], (float)codes_s[1],
                              (float)codes_s[2], (float)codes_s[3]);
        }
        __syncthreads();
    }
}

extern "C" void kernel_launch(void* const* d_in, const int* in_sizes, int n_in,
                              void* d_out, int out_size, void* d_ws, size_t ws_size,
                              hipStream_t stream) {
    const float* residual  = (const float*)d_in[0];
    const float* codebooks = (const float*)d_in[1];
    float* out = (float*)d_out;
    int B = in_sizes[0] / D_DIM;  // 131072

    const size_t E2_BYTES = LK * sizeof(float);          // 16 KB
    const size_t CB_BYTES = (size_t)LKD * 2;             // 1 MB each (hi, lo)

    float*    e2p      = (float*)d_ws;
    __bf16*   cbh      = (__bf16*)((char*)d_ws + E2_BYTES);
    __bf16*   cblo     = (__bf16*)((char*)d_ws + E2_BYTES + CB_BYTES);
    unsigned* flagcnt  = (unsigned*)((char*)d_ws + E2_BYTES + 2 * CB_BYTES);
    unsigned* flaglist = flagcnt + 16;
    unsigned  flagcap  = (unsigned)((ws_size - (E2_BYTES + 2 * CB_BYTES + 64)) / 4);
    if (flagcap > (unsigned)B) flagcap = (unsigned)B;

    hipLaunchKernelGGL(rvq_prep, dim3(LKD / 8 / 256), dim3(256), 0, stream,
                       codebooks, cbh, cblo, e2p, flagcnt);
    hipLaunchKernelGGL(rvq_mfma, dim3(B / 128), dim3(256), 0, stream,
                       residual, codebooks, cbh, cblo, e2p,
                       flagcnt, flaglist, flagcap, out, B);
    hipLaunchKernelGGL(rvq_fixup, dim3(1024), dim3(256), 0, stream,
                       residual, codebooks, e2p, flagcnt, flaglist, flagcap, out, B);
}

// Round 14
// 705.930 us; speedup vs baseline: 5.5977x; 1.0832x over previous
//
#include <hip/hip_runtime.h>
#include <math.h>

// Residual VQ matching a float32 numpy reference (R3/R6/R7/R10/R12-verified):
//   scores = x2 + e2 - 2*(res @ emb.T) in f32, argmin = first-min.
// R14: single-barrier-per-tile pipeline: 3x16KB Bh buffers (stage(t+2) issued
// right after the top barrier), Bl0+Bl1 issued together (L2->reg, ~1500cy to
// land), deterministic counted-vmcnt ladder {16+S, S}. 5-bit index packing
// (margin 4.5e-4 = proven 1.25e-4 + 1.8e-4 pack bound). No launch-bound
// squeeze (R9/R13 lesson). Fixup: 4 independent f64 chains, grid 1024.

#define D_DIM 128
#define K_CB  1024
#define L_LVL 4
#define LK    (L_LVL * K_CB)
#define LKD   (LK * D_DIM)
#define NT2   16               // 16 tiles x 64 codewords
#define TILE_ELEMS 8192        // 64 cw x 128 dims
#define MARGIN_P5 4.5e-4f

typedef __bf16 bf16x8 __attribute__((ext_vector_type(8)));
typedef float  f32x16 __attribute__((ext_vector_type(16)));

// force f32 rounding of a product (blocks fma contraction)
static __device__ __forceinline__ float mulr(float a, float b) {
    float p = a * b; asm volatile("" : "+v"(p)); return p;
}

// ---------------- prep: swizzled bf16 hi/lo + pairwise e2 + flag zero ----------------
// chunk j: lane=j&63, kk=(j>>6)&7, s=(j>>9)&1, t=(j>>10)&15, lv=j>>14
// src row = lv*1024 + t*64 + s*32 + (lane&31), elems kk*16 + (lane>>5)*8 + 0..7
__global__ void rvq_prep(const float* __restrict__ cb,
                         __bf16* __restrict__ hi, __bf16* __restrict__ lo,
                         float* __restrict__ e2p, unsigned* __restrict__ flagcnt) {
    int j = blockIdx.x * blockDim.x + threadIdx.x;   // [0, LKD/8)
    if (j == 0) *flagcnt = 0;
    const int lane = j & 63, kk = (j >> 6) & 7, s = (j >> 9) & 1,
              t = (j >> 10) & 15, lv = j >> 14;
    const int row  = lv * K_CB + t * 64 + s * 32 + (lane & 31);
    const int elem = kk * 16 + (lane >> 5) * 8;
    const float* src = cb + (size_t)row * D_DIM + elem;
    float4 a = *(const float4*)src;
    float4 b = *(const float4*)(src + 4);
    float f[8] = {a.x, a.y, a.z, a.w, b.x, b.y, b.z, b.w};
    bf16x8 hv, lvv;
    #pragma unroll
    for (int e = 0; e < 8; ++e) {
        __bf16 h = (__bf16)f[e];
        hv[e]  = h;
        lvv[e] = (__bf16)(f[e] - (float)h);
    }
    *(bf16x8*)(hi + (size_t)j * 8) = hv;
    *(bf16x8*)(lo + (size_t)j * 8) = lvv;

    if (j < LK) {   // numpy-pairwise ||e||^2 for codeword row j
        const float* ep = cb + (size_t)j * D_DIM;
        float r8[8];
        #pragma unroll
        for (int q = 0; q < 8; ++q) r8[q] = mulr(ep[q], ep[q]);
        #pragma unroll
        for (int bb = 1; bb < 16; ++bb)
            #pragma unroll
            for (int q = 0; q < 8; ++q) r8[q] += mulr(ep[bb * 8 + q], ep[bb * 8 + q]);
        e2p[j] = ((r8[0] + r8[1]) + (r8[2] + r8[3])) + ((r8[4] + r8[5]) + (r8[6] + r8[7]));
    }
}

// ---------------- stage one 64-cw tile's hi into LDS (linear, coalesced) ----------------
static __device__ __forceinline__ void stage_tile(
    const __bf16* srcTile, __bf16* dst, int wave, int lane) {
    #pragma unroll
    for (int c = 0; c < 4; ++c) {
        const int it = wave * 4 + c;   // 1KB chunk id, 0..15
        __builtin_amdgcn_global_load_lds(
            (const __attribute__((address_space(1))) void*)(srcTile + it * 512 + lane * 8),
            (__attribute__((address_space(3))) void*)(dst + it * 512), 16, 0, 0);
    }
}

#define MFMA(A, Bv, C) __builtin_amdgcn_mfma_f32_32x32x16_bf16(A, Bv, C, 0, 0, 0)

// pack idx5 into low-5 mantissa bits, round-to-nearest stomp
static __device__ __forceinline__ float pack5(float sc, unsigned pk5) {
    unsigned u = __float_as_uint(sc);
    return __uint_as_float(((u + 16u) & ~31u) | pk5);
}

// ---------------- MFMA hot kernel ----------------
__global__ __launch_bounds__(256)
void rvq_mfma(const float* __restrict__ residual,
              const float* __restrict__ codebooks,
              const __bf16* __restrict__ cbh, const __bf16* __restrict__ cbl,
              const float* __restrict__ e2p,
              unsigned* __restrict__ flagcnt, unsigned* __restrict__ flaglist,
              unsigned flagcap, float* __restrict__ out, int B) {
    __shared__ __align__(16) __bf16 bufh[3][TILE_ELEMS];   // 3 x 16 KB
    __shared__ float e2s[K_CB];                            // 4 KB
    __shared__ int   bidxs[L_LVL][128];
    __shared__ unsigned char flg[128];

    const int tid  = threadIdx.x;
    const int wave = tid >> 6;
    const int lane = tid & 63;
    const int col  = lane & 31;
    const int h    = lane >> 5;
    const int rb   = wave * 32;
    const int grow = blockIdx.x * 128 + rb + col;

    if (tid < 128) flg[tid] = 0;

    // A fragments: residual row split to bf16 hi/lo, in registers.
    bf16x8 Ah[8], Al[8];
    {
        const float* rowp = residual + (size_t)grow * D_DIM;
        #pragma unroll
        for (int kk = 0; kk < 8; ++kk) {
            const int d0 = kk * 16 + h * 8;
            float4 a = *(const float4*)(rowp + d0);
            float4 b = *(const float4*)(rowp + d0 + 4);
            float f[8] = {a.x, a.y, a.z, a.w, b.x, b.y, b.z, b.w};
            #pragma unroll
            for (int e = 0; e < 8; ++e) {
                __bf16 hh = (__bf16)f[e];
                Ah[kk][e] = hh;
                Al[kk][e] = (__bf16)(f[e] - (float)hh);
            }
        }
    }

    for (int l = 0; l < L_LVL; ++l) {
        const __bf16* cbhL = cbh + (size_t)l * NT2 * TILE_ELEMS;
        const __bf16* cblL = cbl + (size_t)l * NT2 * TILE_ELEMS;

        // level's e2 -> LDS; drain stray vmem (gathers / e2 load / A-build)
        ((float4*)e2s)[tid] = ((const float4*)(e2p + l * K_CB))[tid];
        asm volatile("s_waitcnt vmcnt(0)" ::: "memory");

        // packed top-2 (real packed scores are >= ~2; 0 is safe -inf)
        float rbest[16], rbest2[16];
        #pragma unroll
        for (int s = 0; s < 16; ++s) { rbest[s] = 0.f; rbest2[s] = 0.f; }

        stage_tile(cbhL + 0 * TILE_ELEMS, &bufh[0][0], wave, lane);
        stage_tile(cbhL + 1 * TILE_ELEMS, &bufh[1][0], wave, lane);

        for (int t = 0; t < NT2; ++t) {
            const __bf16* bh  = &bufh[t % 3][0];
            const __bf16* blT = cblL + (size_t)t * TILE_ELEMS;
            const bool haveStage = (t + 2 < NT2);

            if (t == 0) asm volatile("s_waitcnt vmcnt(0) lgkmcnt(0)" ::: "memory");
            // certifies: tile t resident (own quarter waited, others via barrier)
            // AND all waves done reading tile t-1 (buf[(t+2)%3] is free).
            __builtin_amdgcn_s_barrier();
            __builtin_amdgcn_sched_barrier(0);

            // issue Bl0+Bl1 (L2->reg) and stage(t+2) right away
            bf16x8 Bl0[8], Bl1[8];
            #pragma unroll
            for (int kk = 0; kk < 8; ++kk)
                Bl0[kk] = *(const bf16x8*)(blT + kk * 512 + lane * 8);
            #pragma unroll
            for (int kk = 0; kk < 8; ++kk)
                Bl1[kk] = *(const bf16x8*)(blT + 4096 + kk * 512 + lane * 8);
            if (haveStage)
                stage_tile(cbhL + (size_t)(t + 2) * TILE_ELEMS,
                           &bufh[(t + 2) % 3][0], wave, lane);

            // acc init folds e2 and +16 offset: packed score = acc_final
            const float e2i0 = fmaf(-0.5f, e2s[t * 64 + col], 16.f);
            const float e2i1 = fmaf(-0.5f, e2s[t * 64 + 32 + col], 16.f);
            f32x16 acc0, acc1;
            #pragma unroll
            for (int s = 0; s < 16; ++s) { acc0[s] = e2i0; acc1[s] = e2i1; }

            __builtin_amdgcn_s_setprio(1);
            #pragma unroll
            for (int kk = 0; kk < 8; ++kk) {   // Bh passes (LDS), 2 chains
                bf16x8 Bh0 = *(const bf16x8*)(bh + kk * 512 + lane * 8);
                bf16x8 Bh1 = *(const bf16x8*)(bh + 4096 + kk * 512 + lane * 8);
                acc0 = MFMA(Ah[kk], Bh0, acc0);
                acc0 = MFMA(Al[kk], Bh0, acc0);
                acc1 = MFMA(Ah[kk], Bh1, acc1);
                acc1 = MFMA(Al[kk], Bh1, acc1);
            }
            __builtin_amdgcn_s_setprio(0);

            // Bl0 landed: FIFO leaves Bl1(16) + stage(S) outstanding
            if (haveStage) asm volatile("s_waitcnt vmcnt(20)" ::: "memory");
            else           asm volatile("s_waitcnt vmcnt(16)" ::: "memory");
            __builtin_amdgcn_sched_barrier(0);
            __builtin_amdgcn_s_setprio(1);
            #pragma unroll
            for (int kk = 0; kk < 8; ++kk) acc0 = MFMA(Ah[kk], Bl0[kk], acc0);
            __builtin_amdgcn_s_setprio(0);

            // subtile0 top-2 while Bl1 finishes
            const unsigned pk0 = 31u - (unsigned)(t * 2);
            #pragma unroll
            for (int s = 0; s < 16; ++s) {
                float p0 = pack5(acc0[s], pk0);
                rbest2[s] = __builtin_amdgcn_fmed3f(p0, rbest[s], rbest2[s]);
                rbest[s]  = fmaxf(rbest[s], p0);
            }

            // Bl1 landed: leaves only stage(t+2)'s S outstanding
            if (haveStage) asm volatile("s_waitcnt vmcnt(4)" ::: "memory");
            else           asm volatile("s_waitcnt vmcnt(0)" ::: "memory");
            __builtin_amdgcn_sched_barrier(0);
            __builtin_amdgcn_s_setprio(1);
            #pragma unroll
            for (int kk = 0; kk < 8; ++kk) acc1 = MFMA(Ah[kk], Bl1[kk], acc1);
            __builtin_amdgcn_s_setprio(0);

            const unsigned pk1 = 31u - (unsigned)(t * 2 + 1);
            #pragma unroll
            for (int s = 0; s < 16; ++s) {
                float p1 = pack5(acc1[s], pk1);
                rbest2[s] = __builtin_amdgcn_fmed3f(p1, rbest[s], rbest2[s]);
                rbest[s]  = fmaxf(rbest[s], p1);
            }
        }

        // merge across the 32 cols: packed value (score+idx5) + explicit col.
        #pragma unroll
        for (int s = 0; s < 16; ++s) {
            float b = rbest[s], b2 = rbest2[s];
            int   c = col;
            #pragma unroll
            for (int m = 1; m <= 16; m <<= 1) {
                float bo  = __shfl_xor(b,  m, 64);
                float b2o = __shfl_xor(b2, m, 64);
                int   co  = __shfl_xor(c,  m, 64);
                float nb2 = fmaxf(fminf(b, bo), fmaxf(b2, b2o));
                if (bo > b || (bo == b && co < c)) { b = bo; c = co; }
                b2 = nb2;
            }
            const int rloc = (s & 3) + 8 * (s >> 2) + 4 * h;   // verified C row map
            if (col == 0) {
                int idx5 = 31 - (int)(__float_as_uint(b) & 31u);
                bidxs[l][rb + rloc] = idx5 * 32 + c;
                if (b - b2 <= MARGIN_P5) flg[rb + rloc] = 1;
            }
        }
        __syncthreads();

        // residual update in f32 from exact codebook, re-split to bf16 pair
        {
            const int bi = bidxs[l][rb + col];
            const float* qp = codebooks + ((size_t)l * K_CB + bi) * D_DIM;
            #pragma unroll
            for (int kk = 0; kk < 8; ++kk) {
                const int d0 = kk * 16 + h * 8;
                float4 qa = *(const float4*)(qp + d0);
                float4 qb = *(const float4*)(qp + d0 + 4);
                float q[8] = {qa.x, qa.y, qa.z, qa.w, qb.x, qb.y, qb.z, qb.w};
                #pragma unroll
                for (int e = 0; e < 8; ++e) {
                    float r = ((float)Ah[kk][e] + (float)Al[kk][e]) - q[e];
                    __bf16 hh = (__bf16)r;
                    Ah[kk][e] = hh;
                    Al[kk][e] = (__bf16)(r - (float)hh);
                }
            }
        }
    }

    // quantized = r0 - r_final
    {
        const float* rowp = residual + (size_t)grow * D_DIM;
        float* op = out + (size_t)grow * D_DIM;
        #pragma unroll
        for (int kk = 0; kk < 8; ++kk) {
            const int d0 = kk * 16 + h * 8;
            float4 a = *(const float4*)(rowp + d0);
            float4 b = *(const float4*)(rowp + d0 + 4);
            float f[8] = {a.x, a.y, a.z, a.w, b.x, b.y, b.z, b.w};
            float o[8];
            #pragma unroll
            for (int e = 0; e < 8; ++e)
                o[e] = f[e] - ((float)Ah[kk][e] + (float)Al[kk][e]);
            *(float4*)(op + d0)     = make_float4(o[0], o[1], o[2], o[3]);
            *(float4*)(op + d0 + 4) = make_float4(o[4], o[5], o[6], o[7]);
        }
    }
    if (tid < 128) {
        int row = blockIdx.x * 128 + tid;
        float4* cp = (float4*)(out + (size_t)B * D_DIM + (size_t)row * L_LVL);
        *cp = make_float4((float)bidxs[0][tid], (float)bidxs[1][tid],
                          (float)bidxs[2][tid], (float)bidxs[3][tid]);
        if (flg[tid]) {
            unsigned pos = atomicAdd(flagcnt, 1u);
            if (pos < flagcap) flaglist[pos] = row;
        }
    }
}

// ---------------- fixup: replicated reference semantics per flagged row ----------------
__global__ __launch_bounds__(256, 1)
void rvq_fixup(const float* __restrict__ residual,
               const float* __restrict__ codebooks,
               const float* __restrict__ e2p,
               const unsigned* __restrict__ flagcnt,
               const unsigned* __restrict__ flaglist,
               unsigned flagcap, float* __restrict__ out, int B) {
    __shared__ float rbuf[D_DIM];
    __shared__ float r0buf[D_DIM];
    __shared__ float x2s;
    __shared__ float redS[256];
    __shared__ int   redK[256];
    __shared__ int   codes_s[L_LVL];

    unsigned n = *flagcnt;
    if (n > flagcap) n = flagcap;

    for (unsigned b = blockIdx.x; b < n; b += gridDim.x) {
        int row = (int)flaglist[b];
        if (threadIdx.x < 32) {
            float4 v = ((const float4*)(residual + (size_t)row * D_DIM))[threadIdx.x];
            *(float4*)&rbuf[threadIdx.x * 4]  = v;
            *(float4*)&r0buf[threadIdx.x * 4] = v;
        }
        __syncthreads();

        for (int l = 0; l < L_LVL; ++l) {
            const float* cbl = codebooks + (size_t)l * K_CB * D_DIM;
            if (threadIdx.x == 0) {
                float r8[8];
                #pragma unroll
                for (int q = 0; q < 8; ++q) r8[q] = mulr(rbuf[q], rbuf[q]);
                for (int bb = 1; bb < 16; ++bb)
                    #pragma unroll
                    for (int q = 0; q < 8; ++q) r8[q] += mulr(rbuf[bb * 8 + q], rbuf[bb * 8 + q]);
                x2s = ((r8[0] + r8[1]) + (r8[2] + r8[3])) + ((r8[4] + r8[5]) + (r8[6] + r8[7]));
            }
            __syncthreads();
            float x2 = x2s;

            float bS = 3.4e38f;
            int   bK = 0x7fffffff;
            for (int m = 0; m < 4; ++m) {
                int k = threadIdx.x + m * 256;
                const float4* ek = (const float4*)(cbl + (size_t)k * D_DIM);
                // 4 independent f64 chains (reorder noise ~2^-50 << f32 ulp)
                double dd0 = 0.0, dd1 = 0.0, dd2 = 0.0, dd3 = 0.0;
                for (int c = 0; c < 32; c += 4) {
                    float4 v0 = ek[c], v1 = ek[c + 1], v2 = ek[c + 2], v3 = ek[c + 3];
                    dd0 = fma((double)v0.x, (double)rbuf[c * 4 + 0], dd0);
                    dd0 = fma((double)v0.y, (double)rbuf[c * 4 + 1], dd0);
                    dd0 = fma((double)v0.z, (double)rbuf[c * 4 + 2], dd0);
                    dd0 = fma((double)v0.w, (double)rbuf[c * 4 + 3], dd0);
                    dd1 = fma((double)v1.x, (double)rbuf[c * 4 + 4], dd1);
                    dd1 = fma((double)v1.y, (double)rbuf[c * 4 + 5], dd1);
                    dd1 = fma((double)v1.z, (double)rbuf[c * 4 + 6], dd1);
                    dd1 = fma((double)v1.w, (double)rbuf[c * 4 + 7], dd1);
                    dd2 = fma((double)v2.x, (double)rbuf[c * 4 + 8], dd2);
                    dd2 = fma((double)v2.y, (double)rbuf[c * 4 + 9], dd2);
                    dd2 = fma((double)v2.z, (double)rbuf[c * 4 + 10], dd2);
                    dd2 = fma((double)v2.w, (double)rbuf[c * 4 + 11], dd2);
                    dd3 = fma((double)v3.x, (double)rbuf[c * 4 + 12], dd3);
                    dd3 = fma((double)v3.y, (double)rbuf[c * 4 + 13], dd3);
                    dd3 = fma((double)v3.z, (double)rbuf[c * 4 + 14], dd3);
                    dd3 = fma((double)v3.w, (double)rbuf[c * 4 + 15], dd3);
                }
                float M = (float)((dd0 + dd1) + (dd2 + dd3));  // fl32(exact dot)
                float A = x2 + e2p[l * K_CB + k];    // fl32(x2 + e2)
                float S = A - 2.0f * M;              // final f32 rounding
                if (S < bS || (S == bS && k < bK)) { bS = S; bK = k; }
            }
            redS[threadIdx.x] = bS; redK[threadIdx.x] = bK;
            __syncthreads();
            for (int s = 128; s > 0; s >>= 1) {
                if (threadIdx.x < (unsigned)s) {
                    float So = redS[threadIdx.x + s];
                    int   Ko = redK[threadIdx.x + s];
                    if (So < redS[threadIdx.x] ||
                        (So == redS[threadIdx.x] && Ko < redK[threadIdx.x])) {
                        redS[threadIdx.x] = So; redK[threadIdx.x] = Ko;
                    }
                }
                __syncthreads();
            }
            int bi = redK[0];
            if (threadIdx.x == 0) codes_s[l] = bi;
            if (threadIdx.x < 32) {
                float4 q = ((const float4*)(cbl + (size_t)bi * D_DIM))[threadIdx.x];
                float4* p = (float4*)&rbuf[threadIdx.x * 4];
                float4 x = *p;
                x.x -= q.x; x.y -= q.y; x.z -= q.z; x.w -= q.w;
                *p = x;
            }
            __syncthreads();
        }

        if (threadIdx.x < 32) {
            float4 a = *(float4*)&r0buf[threadIdx.x * 4];
            float4 r = *(float4*)&rbuf[threadIdx.x * 4];
            ((float4*)(out + (size_t)row * D_DIM))[threadIdx.x] =
                make_float4(a.x - r.x, a.y - r.y, a.z - r.z, a.w - r.w);
        }
        if (threadIdx.x == 0) {
            float4* cp = (float4*)(out + (size_t)B * D_DIM + (size_t)row * L_LVL);
            *cp = make_float4((float)codes_s[0], (float)codes_s[1],
                              (float)codes_s[2], (float)codes_s[3]);
        }
        __syncthreads();
    }
}

extern "C" void kernel_launch(void* const* d_in, const int* in_sizes, int n_in,
                              void* d_out, int out_size, void* d_ws, size_t ws_size,
                              hipStream_t stream) {
    const float* residual  = (const float*)d_in[0];
    const float* codebooks = (const float*)d_in[1];
    float* out = (float*)d_out;
    int B = in_sizes[0] / D_DIM;  // 131072

    const size_t E2_BYTES = LK * sizeof(float);          // 16 KB
    const size_t CB_BYTES = (size_t)LKD * 2;             // 1 MB each (hi, lo)

    float*    e2p      = (float*)d_ws;
    __bf16*   cbh      = (__bf16*)((char*)d_ws + E2_BYTES);
    __bf16*   cblo     = (__bf16*)((char*)d_ws + E2_BYTES + CB_BYTES);
    unsigned* flagcnt  = (unsigned*)((char*)d_ws + E2_BYTES + 2 * CB_BYTES);
    unsigned* flaglist = flagcnt + 16;
    unsigned  flagcap  = (unsigned)((ws_size - (E2_BYTES + 2 * CB_BYTES + 64)) / 4);
    if (flagcap > (unsigned)B) flagcap = (unsigned)B;

    hipLaunchKernelGGL(rvq_prep, dim3(LKD / 8 / 256), dim3(256), 0, stream,
                       codebooks, cbh, cblo, e2p, flagcnt);
    hipLaunchKernelGGL(rvq_mfma, dim3(B / 128), dim3(256), 0, stream,
                       residual, codebooks, cbh, cblo, e2p,
                       flagcnt, flaglist, flagcap, out, B);
    hipLaunchKernelGGL(rvq_fixup, dim3(1024), dim3(256), 0, stream,
                       residual, codebooks, e2p, flagcnt, flaglist, flagcap, out, B);
}

// Round 15
// 638.479 us; speedup vs baseline: 6.1891x; 1.1056x over previous
//
#include <hip/hip_runtime.h>
#include <math.h>

// Residual VQ matching a float32 numpy reference (R3/R6/R7/R10/R12-verified):
//   scores = x2 + e2 - 2*(res @ emb.T) in f32, argmin = first-min.
// R15: hot kernel = R12 verbatim (best measured: 533us, MfmaUtil 35.5%).
// Fixup v2: bf16-hi screen (half the bytes, f32 ALU) + exact f64 rescore only
// for candidates within a rigorous CS margin 2*(||r||*max||e_lo|| + 1e-4);
// max||e_lo|| per level computed in prep (atomicMax on float-as-uint).

#define D_DIM 128
#define K_CB  1024
#define L_LVL 4
#define LK    (L_LVL * K_CB)
#define LKD   (LK * D_DIM)
#define NT2   16               // 16 tiles x 64 codewords
#define TILE_ELEMS 8192        // 64 cw x 128 dims
#define MARGIN_P5 4.5e-4f      // acc-domain; passed R12/R13/R14

typedef __bf16 bf16x8 __attribute__((ext_vector_type(8)));
typedef float  f32x16 __attribute__((ext_vector_type(16)));

// force f32 rounding of a product (blocks fma contraction)
static __device__ __forceinline__ float mulr(float a, float b) {
    float p = a * b; asm volatile("" : "+v"(p)); return p;
}

// ---------------- prep: swizzled bf16 hi/lo + pairwise e2 + elo-norm max ----------------
// chunk j: lane=j&63, kk=(j>>6)&7, s=(j>>9)&1, t=(j>>10)&15, lv=j>>14
// src row = lv*1024 + t*64 + s*32 + (lane&31), elems kk*16 + (lane>>5)*8 + 0..7
__global__ void rvq_prep(const float* __restrict__ cb,
                         __bf16* __restrict__ hi, __bf16* __restrict__ lo,
                         float* __restrict__ e2p, unsigned* __restrict__ flagcnt) {
    int j = blockIdx.x * blockDim.x + threadIdx.x;   // [0, LKD/8)
    const int lane = j & 63, kk = (j >> 6) & 7, s = (j >> 9) & 1,
              t = (j >> 10) & 15, lv = j >> 14;
    const int row  = lv * K_CB + t * 64 + s * 32 + (lane & 31);
    const int elem = kk * 16 + (lane >> 5) * 8;
    const float* src = cb + (size_t)row * D_DIM + elem;
    float4 a = *(const float4*)src;
    float4 b = *(const float4*)(src + 4);
    float f[8] = {a.x, a.y, a.z, a.w, b.x, b.y, b.z, b.w};
    bf16x8 hv, lvv;
    #pragma unroll
    for (int e = 0; e < 8; ++e) {
        __bf16 h = (__bf16)f[e];
        hv[e]  = h;
        lvv[e] = (__bf16)(f[e] - (float)h);
    }
    *(bf16x8*)(hi + (size_t)j * 8) = hv;
    *(bf16x8*)(lo + (size_t)j * 8) = lvv;

    if (j < LK) {   // numpy-pairwise ||e||^2 for codeword row j, + max ||e_lo||
        const float* ep = cb + (size_t)j * D_DIM;
        float r8[8];
        #pragma unroll
        for (int q = 0; q < 8; ++q) r8[q] = mulr(ep[q], ep[q]);
        #pragma unroll
        for (int bb = 1; bb < 16; ++bb)
            #pragma unroll
            for (int q = 0; q < 8; ++q) r8[q] += mulr(ep[bb * 8 + q], ep[bb * 8 + q]);
        e2p[j] = ((r8[0] + r8[1]) + (r8[2] + r8[3])) + ((r8[4] + r8[5]) + (r8[6] + r8[7]));

        float lsum = 0.f;
        for (int q2 = 0; q2 < D_DIM; ++q2) {
            float v = ep[q2];
            __bf16 hh = (__bf16)v;
            float dl = v - (float)hh;
            lsum = fmaf(dl, dl, lsum);
        }
        unsigned* elmaxu = flagcnt + 4;   // elmax[0..3] live at flagcnt+4..7
        atomicMax(&elmaxu[j >> 10], __float_as_uint(sqrtf(lsum)));
    }
}

// ---------------- stage one 64-cw tile's hi into LDS (linear, coalesced) ----------------
static __device__ __forceinline__ void stage_tile(
    const __bf16* srcTile, __bf16* dst, int wave, int lane) {
    #pragma unroll
    for (int c = 0; c < 4; ++c) {
        const int it = wave * 4 + c;   // 1KB chunk id, 0..15
        __builtin_amdgcn_global_load_lds(
            (const __attribute__((address_space(1))) void*)(srcTile + it * 512 + lane * 8),
            (__attribute__((address_space(3))) void*)(dst + it * 512), 16, 0, 0);
    }
}

#define MFMA(A, Bv, C) __builtin_amdgcn_mfma_f32_32x32x16_bf16(A, Bv, C, 0, 0, 0)

// pack idx5 into low-5 mantissa bits, round-to-nearest stomp
static __device__ __forceinline__ float pack5(float sc, unsigned pk5) {
    unsigned u = __float_as_uint(sc);
    return __uint_as_float(((u + 16u) & ~31u) | pk5);
}

// ---------------- MFMA hot kernel (R12 verbatim) ----------------
__global__ __launch_bounds__(256)
void rvq_mfma(const float* __restrict__ residual,
              const float* __restrict__ codebooks,
              const __bf16* __restrict__ cbh, const __bf16* __restrict__ cbl,
              const float* __restrict__ e2p,
              unsigned* __restrict__ flagcnt, unsigned* __restrict__ flaglist,
              unsigned flagcap, float* __restrict__ out, int B) {
    __shared__ __align__(16) __bf16 bufh[2][TILE_ELEMS];   // 2 x 16 KB
    __shared__ float e2s[K_CB];                            // 4 KB
    __shared__ int   bidxs[L_LVL][128];
    __shared__ unsigned char flg[128];

    const int tid  = threadIdx.x;
    const int wave = tid >> 6;
    const int lane = tid & 63;
    const int col  = lane & 31;
    const int h    = lane >> 5;
    const int rb   = wave * 32;
    const int grow = blockIdx.x * 128 + rb + col;

    if (tid < 128) flg[tid] = 0;

    // A fragments: residual row split to bf16 hi/lo, in registers.
    bf16x8 Ah[8], Al[8];
    {
        const float* rowp = residual + (size_t)grow * D_DIM;
        #pragma unroll
        for (int kk = 0; kk < 8; ++kk) {
            const int d0 = kk * 16 + h * 8;
            float4 a = *(const float4*)(rowp + d0);
            float4 b = *(const float4*)(rowp + d0 + 4);
            float f[8] = {a.x, a.y, a.z, a.w, b.x, b.y, b.z, b.w};
            #pragma unroll
            for (int e = 0; e < 8; ++e) {
                __bf16 hh = (__bf16)f[e];
                Ah[kk][e] = hh;
                Al[kk][e] = (__bf16)(f[e] - (float)hh);
            }
        }
    }

    for (int l = 0; l < L_LVL; ++l) {
        const __bf16* cbhL = cbh + (size_t)l * NT2 * TILE_ELEMS;
        const __bf16* cblL = cbl + (size_t)l * NT2 * TILE_ELEMS;

        // level's e2 -> LDS, drain all stray vmem (gathers/A-build)
        ((float4*)e2s)[tid] = ((const float4*)(e2p + l * K_CB))[tid];
        asm volatile("s_waitcnt vmcnt(0)" ::: "memory");

        // packed top-2 (real packed scores are >= ~2; 0 is safe -inf)
        float rbest[16], rbest2[16];
        #pragma unroll
        for (int s = 0; s < 16; ++s) { rbest[s] = 0.f; rbest2[s] = 0.f; }

        stage_tile(cbhL + 0 * TILE_ELEMS, &bufh[0][0], wave, lane);
        stage_tile(cbhL + 1 * TILE_ELEMS, &bufh[1][0], wave, lane);

        for (int t = 0; t < NT2; ++t) {
            const int cur = t & 1;
            const __bf16* bh  = &bufh[cur][0];
            const __bf16* blT = cblL + (size_t)t * TILE_ELEMS;

            if (t == 0) asm volatile("s_waitcnt vmcnt(4) lgkmcnt(0)" ::: "memory");
            __builtin_amdgcn_s_barrier();      // tile t resident; e2s visible
            __builtin_amdgcn_sched_barrier(0);

            // issue Bl0 (subtile0 lo) early; lands under the 32 Bh MFMAs
            bf16x8 Blr[8];
            #pragma unroll
            for (int kk = 0; kk < 8; ++kk)
                Blr[kk] = *(const bf16x8*)(blT + kk * 512 + lane * 8);

            // acc init folds e2 and +16 offset: packed score = acc_final
            const float e2i0 = fmaf(-0.5f, e2s[t * 64 + col], 16.f);
            const float e2i1 = fmaf(-0.5f, e2s[t * 64 + 32 + col], 16.f);
            f32x16 acc0, acc1;
            #pragma unroll
            for (int s = 0; s < 16; ++s) { acc0[s] = e2i0; acc1[s] = e2i1; }

            __builtin_amdgcn_s_setprio(1);
            #pragma unroll
            for (int kk = 0; kk < 8; ++kk) {   // Bh passes, 2 chains interleaved
                bf16x8 Bh0 = *(const bf16x8*)(bh + kk * 512 + lane * 8);
                bf16x8 Bh1 = *(const bf16x8*)(bh + 4096 + kk * 512 + lane * 8);
                acc0 = MFMA(Ah[kk], Bh0, acc0);
                acc0 = MFMA(Al[kk], Bh0, acc0);
                acc1 = MFMA(Ah[kk], Bh1, acc1);
                acc1 = MFMA(Al[kk], Bh1, acc1);
            }
            // Bl0 landed (also drains stage(t+1), issued >1 iteration ago)
            asm volatile("s_waitcnt vmcnt(0)" ::: "memory");
            __builtin_amdgcn_sched_barrier(0);
            #pragma unroll
            for (int kk = 0; kk < 8; ++kk) acc0 = MFMA(Ah[kk], Blr[kk], acc0);
            __builtin_amdgcn_s_setprio(0);

            // reload Blr with subtile1 lo (hidden under barrier + stage issue
            // + subtile0 scoring)
            #pragma unroll
            for (int kk = 0; kk < 8; ++kk)
                Blr[kk] = *(const bf16x8*)(blT + 4096 + kk * 512 + lane * 8);

            __builtin_amdgcn_sched_barrier(0);
            __builtin_amdgcn_s_barrier();      // all waves done reading bufh[cur]
            asm volatile("" ::: "memory");
            if (t + 2 < NT2)
                stage_tile(cbhL + (size_t)(t + 2) * TILE_ELEMS, &bufh[cur][0], wave, lane);

            // subtile0 top-2 while Bl1 in flight
            const unsigned pk0 = 31u - (unsigned)(t * 2);
            #pragma unroll
            for (int s = 0; s < 16; ++s) {
                float p0 = pack5(acc0[s], pk0);
                rbest2[s] = __builtin_amdgcn_fmed3f(p0, rbest[s], rbest2[s]);
                rbest[s]  = fmaxf(rbest[s], p0);
            }

            // Bl1 landed; stage(t+2)'s 4 stay in flight (counted)
            if (t + 2 < NT2) asm volatile("s_waitcnt vmcnt(4)" ::: "memory");
            else             asm volatile("s_waitcnt vmcnt(0)" ::: "memory");
            __builtin_amdgcn_sched_barrier(0);
            __builtin_amdgcn_s_setprio(1);
            #pragma unroll
            for (int kk = 0; kk < 8; ++kk) acc1 = MFMA(Ah[kk], Blr[kk], acc1);
            __builtin_amdgcn_s_setprio(0);

            const unsigned pk1 = 31u - (unsigned)(t * 2 + 1);
            #pragma unroll
            for (int s = 0; s < 16; ++s) {
                float p1 = pack5(acc1[s], pk1);
                rbest2[s] = __builtin_amdgcn_fmed3f(p1, rbest[s], rbest2[s]);
                rbest[s]  = fmaxf(rbest[s], p1);
            }
        }

        // merge across the 32 cols: packed value (score+idx5) + explicit col.
        #pragma unroll
        for (int s = 0; s < 16; ++s) {
            float b = rbest[s], b2 = rbest2[s];
            int   c = col;
            #pragma unroll
            for (int m = 1; m <= 16; m <<= 1) {
                float bo  = __shfl_xor(b,  m, 64);
                float b2o = __shfl_xor(b2, m, 64);
                int   co  = __shfl_xor(c,  m, 64);
                float nb2 = fmaxf(fminf(b, bo), fmaxf(b2, b2o));
                if (bo > b || (bo == b && co < c)) { b = bo; c = co; }
                b2 = nb2;
            }
            const int rloc = (s & 3) + 8 * (s >> 2) + 4 * h;   // verified C row map
            if (col == 0) {
                int idx5 = 31 - (int)(__float_as_uint(b) & 31u);
                bidxs[l][rb + rloc] = idx5 * 32 + c;
                if (b - b2 <= MARGIN_P5) flg[rb + rloc] = 1;
            }
        }
        __syncthreads();

        // residual update in f32 from exact codebook, re-split to bf16 pair
        {
            const int bi = bidxs[l][rb + col];
            const float* qp = codebooks + ((size_t)l * K_CB + bi) * D_DIM;
            #pragma unroll
            for (int kk = 0; kk < 8; ++kk) {
                const int d0 = kk * 16 + h * 8;
                float4 qa = *(const float4*)(qp + d0);
                float4 qb = *(const float4*)(qp + d0 + 4);
                float q[8] = {qa.x, qa.y, qa.z, qa.w, qb.x, qb.y, qb.z, qb.w};
                #pragma unroll
                for (int e = 0; e < 8; ++e) {
                    float r = ((float)Ah[kk][e] + (float)Al[kk][e]) - q[e];
                    __bf16 hh = (__bf16)r;
                    Ah[kk][e] = hh;
                    Al[kk][e] = (__bf16)(r - (float)hh);
                }
            }
        }
    }

    // quantized = r0 - r_final
    {
        const float* rowp = residual + (size_t)grow * D_DIM;
        float* op = out + (size_t)grow * D_DIM;
        #pragma unroll
        for (int kk = 0; kk < 8; ++kk) {
            const int d0 = kk * 16 + h * 8;
            float4 a = *(const float4*)(rowp + d0);
            float4 b = *(const float4*)(rowp + d0 + 4);
            float f[8] = {a.x, a.y, a.z, a.w, b.x, b.y, b.z, b.w};
            float o[8];
            #pragma unroll
            for (int e = 0; e < 8; ++e)
                o[e] = f[e] - ((float)Ah[kk][e] + (float)Al[kk][e]);
            *(float4*)(op + d0)     = make_float4(o[0], o[1], o[2], o[3]);
            *(float4*)(op + d0 + 4) = make_float4(o[4], o[5], o[6], o[7]);
        }
    }
    if (tid < 128) {
        int row = blockIdx.x * 128 + tid;
        float4* cp = (float4*)(out + (size_t)B * D_DIM + (size_t)row * L_LVL);
        *cp = make_float4((float)bidxs[0][tid], (float)bidxs[1][tid],
                          (float)bidxs[2][tid], (float)bidxs[3][tid]);
        if (flg[tid]) {
            unsigned pos = atomicAdd(flagcnt, 1u);
            if (pos < flagcap) flaglist[pos] = row;
        }
    }
}

// ---------------- fixup v2: bf16-hi screen + exact rescore of candidates ----------------
__global__ __launch_bounds__(256, 1)
void rvq_fixup(const float* __restrict__ residual,
               const float* __restrict__ codebooks,
               const __bf16* __restrict__ cbh,
               const float* __restrict__ e2p,
               const unsigned* __restrict__ flagcnt,
               const unsigned* __restrict__ flaglist,
               unsigned flagcap, float* __restrict__ out, int B) {
    __shared__ float rbuf[D_DIM];
    __shared__ float r0buf[D_DIM];
    __shared__ float x2s, smins;
    __shared__ float redS[256];
    __shared__ int   redK[256];
    __shared__ int   codes_s[L_LVL];

    const float* elmax = (const float*)(flagcnt + 4);
    unsigned n = *flagcnt;
    if (n > flagcap) n = flagcap;

    for (unsigned b = blockIdx.x; b < n; b += gridDim.x) {
        int row = (int)flaglist[b];
        if (threadIdx.x < 32) {
            float4 v = ((const float4*)(residual + (size_t)row * D_DIM))[threadIdx.x];
            *(float4*)&rbuf[threadIdx.x * 4]  = v;
            *(float4*)&r0buf[threadIdx.x * 4] = v;
        }
        __syncthreads();

        for (int l = 0; l < L_LVL; ++l) {
            const float* cbl = codebooks + (size_t)l * K_CB * D_DIM;
            const __bf16* cbhL = cbh + (size_t)l * NT2 * TILE_ELEMS;
            if (threadIdx.x == 0) {
                float r8[8];
                #pragma unroll
                for (int q = 0; q < 8; ++q) r8[q] = mulr(rbuf[q], rbuf[q]);
                for (int bb = 1; bb < 16; ++bb)
                    #pragma unroll
                    for (int q = 0; q < 8; ++q) r8[q] += mulr(rbuf[bb * 8 + q], rbuf[bb * 8 + q]);
                x2s = ((r8[0] + r8[1]) + (r8[2] + r8[3])) + ((r8[4] + r8[5]) + (r8[6] + r8[7]));
            }
            __syncthreads();
            float x2 = x2s;

            // ---- screen: bf16-hi scores (f32, 4 chains), track own-min ----
            float s4[4];
            float sm = 3.4e38f;
            #pragma unroll
            for (int m = 0; m < 4; ++m) {
                int k = threadIdx.x + m * 256;
                int t = k >> 6, s = (k >> 5) & 1, c = k & 31;
                const __bf16* kb = cbhL + t * 8192 + s * 4096 + c * 8;
                float c0 = 0.f, c1 = 0.f, c2 = 0.f, c3 = 0.f;
                #pragma unroll
                for (int kk = 0; kk < 8; ++kk) {
                    bf16x8 a  = *(const bf16x8*)(kb + kk * 512);        // elems kk*16+0..7
                    bf16x8 bb = *(const bf16x8*)(kb + kk * 512 + 256);  // elems kk*16+8..15
                    const float* rp = rbuf + kk * 16;
                    c0 = fmaf((float)a[0], rp[0], c0);  c1 = fmaf((float)a[1], rp[1], c1);
                    c2 = fmaf((float)a[2], rp[2], c2);  c3 = fmaf((float)a[3], rp[3], c3);
                    c0 = fmaf((float)a[4], rp[4], c0);  c1 = fmaf((float)a[5], rp[5], c1);
                    c2 = fmaf((float)a[6], rp[6], c2);  c3 = fmaf((float)a[7], rp[7], c3);
                    c0 = fmaf((float)bb[0], rp[8], c0); c1 = fmaf((float)bb[1], rp[9], c1);
                    c2 = fmaf((float)bb[2], rp[10], c2);c3 = fmaf((float)bb[3], rp[11], c3);
                    c0 = fmaf((float)bb[4], rp[12], c0);c1 = fmaf((float)bb[5], rp[13], c1);
                    c2 = fmaf((float)bb[6], rp[14], c2);c3 = fmaf((float)bb[7], rp[15], c3);
                }
                float Mh = (c0 + c1) + (c2 + c3);
                float S = (x2 + e2p[l * K_CB + k]) - 2.0f * Mh;
                s4[m] = S;
                sm = fminf(sm, S);
            }
            redS[threadIdx.x] = sm;
            __syncthreads();
            for (int s = 128; s > 0; s >>= 1) {
                if (threadIdx.x < (unsigned)s)
                    redS[threadIdx.x] = fminf(redS[threadIdx.x], redS[threadIdx.x + s]);
                __syncthreads();
            }
            if (threadIdx.x == 0) smins = redS[0];
            __syncthreads();
            // rigorous candidate threshold: |screen-true| <= ||r||*||e_lo|| + accum
            const float thr = smins + 2.0f * (sqrtf(x2) * elmax[l] + 1e-4f);

            // ---- exact pass for candidates only ----
            float bS = 3.4e38f;
            int   bK = 0x7fffffff;
            #pragma unroll
            for (int m = 0; m < 4; ++m) {
                if (s4[m] > thr) continue;
                int k = threadIdx.x + m * 256;
                const float4* ek = (const float4*)(cbl + (size_t)k * D_DIM);
                double dd0 = 0.0, dd1 = 0.0, dd2 = 0.0, dd3 = 0.0;
                for (int c = 0; c < 32; c += 4) {
                    float4 v0 = ek[c], v1 = ek[c + 1], v2 = ek[c + 2], v3 = ek[c + 3];
                    dd0 = fma((double)v0.x, (double)rbuf[c * 4 + 0], dd0);
                    dd0 = fma((double)v0.y, (double)rbuf[c * 4 + 1], dd0);
                    dd0 = fma((double)v0.z, (double)rbuf[c * 4 + 2], dd0);
                    dd0 = fma((double)v0.w, (double)rbuf[c * 4 + 3], dd0);
                    dd1 = fma((double)v1.x, (double)rbuf[c * 4 + 4], dd1);
                    dd1 = fma((double)v1.y, (double)rbuf[c * 4 + 5], dd1);
                    dd1 = fma((double)v1.z, (double)rbuf[c * 4 + 6], dd1);
                    dd1 = fma((double)v1.w, (double)rbuf[c * 4 + 7], dd1);
                    dd2 = fma((double)v2.x, (double)rbuf[c * 4 + 8], dd2);
                    dd2 = fma((double)v2.y, (double)rbuf[c * 4 + 9], dd2);
                    dd2 = fma((double)v2.z, (double)rbuf[c * 4 + 10], dd2);
                    dd2 = fma((double)v2.w, (double)rbuf[c * 4 + 11], dd2);
                    dd3 = fma((double)v3.x, (double)rbuf[c * 4 + 12], dd3);
                    dd3 = fma((double)v3.y, (double)rbuf[c * 4 + 13], dd3);
                    dd3 = fma((double)v3.z, (double)rbuf[c * 4 + 14], dd3);
                    dd3 = fma((double)v3.w, (double)rbuf[c * 4 + 15], dd3);
                }
                float M = (float)((dd0 + dd1) + (dd2 + dd3));  // fl32(exact dot)
                float A = x2 + e2p[l * K_CB + k];    // fl32(x2 + e2)
                float S = A - 2.0f * M;              // final f32 rounding
                if (S < bS || (S == bS && k < bK)) { bS = S; bK = k; }
            }
            redS[threadIdx.x] = bS; redK[threadIdx.x] = bK;
            __syncthreads();
            for (int s = 128; s > 0; s >>= 1) {
                if (threadIdx.x < (unsigned)s) {
                    float So = redS[threadIdx.x + s];
                    int   Ko = redK[threadIdx.x + s];
                    if (So < redS[threadIdx.x] ||
                        (So == redS[threadIdx.x] && Ko < redK[threadIdx.x])) {
                        redS[threadIdx.x] = So; redK[threadIdx.x] = Ko;
                    }
                }
                __syncthreads();
            }
            int bi = redK[0];
            if (threadIdx.x == 0) codes_s[l] = bi;
            if (threadIdx.x < 32) {
                float4 q = ((const float4*)(cbl + (size_t)bi * D_DIM))[threadIdx.x];
                float4* p = (float4*)&rbuf[threadIdx.x * 4];
                float4 x = *p;
                x.x -= q.x; x.y -= q.y; x.z -= q.z; x.w -= q.w;
                *p = x;
            }
            __syncthreads();
        }

        if (threadIdx.x < 32) {
            float4 a = *(float4*)&r0buf[threadIdx.x * 4];
            float4 r = *(float4*)&rbuf[threadIdx.x * 4];
            ((float4*)(out + (size_t)row * D_DIM))[threadIdx.x] =
                make_float4(a.x - r.x, a.y - r.y, a.z - r.z, a.w - r.w);
        }
        if (threadIdx.x == 0) {
            float4* cp = (float4*)(out + (size_t)B * D_DIM + (size_t)row * L_LVL);
            *cp = make_float4((float)codes_s[0], (float)codes_s[1],
                              (float)codes_s[2], (float)codes_s[3]);
        }
        __syncthreads();
    }
}

extern "C" void kernel_launch(void* const* d_in, const int* in_sizes, int n_in,
                              void* d_out, int out_size, void* d_ws, size_t ws_size,
                              hipStream_t stream) {
    const float* residual  = (const float*)d_in[0];
    const float* codebooks = (const float*)d_in[1];
    float* out = (float*)d_out;
    int B = in_sizes[0] / D_DIM;  // 131072

    const size_t E2_BYTES = LK * sizeof(float);          // 16 KB
    const size_t CB_BYTES = (size_t)LKD * 2;             // 1 MB each (hi, lo)

    float*    e2p      = (float*)d_ws;
    __bf16*   cbh      = (__bf16*)((char*)d_ws + E2_BYTES);
    __bf16*   cblo     = (__bf16*)((char*)d_ws + E2_BYTES + CB_BYTES);
    unsigned* flagcnt  = (unsigned*)((char*)d_ws + E2_BYTES + 2 * CB_BYTES);
    unsigned* flaglist = flagcnt + 16;
    unsigned  flagcap  = (unsigned)((ws_size - (E2_BYTES + 2 * CB_BYTES + 64)) / 4);
    if (flagcap > (unsigned)B) flagcap = (unsigned)B;

    // zero flag count + per-level max||e_lo|| slots (flagcnt[0..7])
    hipMemsetAsync(flagcnt, 0, 32, stream);
    hipLaunchKernelGGL(rvq_prep, dim3(LKD / 8 / 256), dim3(256), 0, stream,
                       codebooks, cbh, cblo, e2p, flagcnt);
    hipLaunchKernelGGL(rvq_mfma, dim3(B / 128), dim3(256), 0, stream,
                       residual, codebooks, cbh, cblo, e2p,
                       flagcnt, flaglist, flagcap, out, B);
    hipLaunchKernelGGL(rvq_fixup, dim3(1024), dim3(256), 0, stream,
                       residual, codebooks, cbh, e2p,
                       flagcnt, flaglist, flagcap, out, B);
}